// Round 1
// baseline (5061.041 us; speedup 1.0000x reference)
//
#include <hip/hip_runtime.h>
#include <math.h>

// ---- problem dims ----
#define BATCH 4
#define NP 1024
#define ND 256
#define NTOT 1280
#define CDIM 1024
#define NH 16
#define DHD 64
#define HID 2730
#define N12 5460
#define N6C 6144
#define EPSF 1e-6f

// ---- workspace layout (float offsets). Total 52,559,872 floats = 210 MB ----
// h12 reuses the [xc..V] region which is dead by mlp1 time.
#define OFF_SC     0            //   4096  silu(c)
#define OFF_ADAP   4096         //  24576  ada_p (4 x 6144)
#define OFF_ADAD   28672        //  24576  ada_d
#define OFF_ROPE   53248        //  65536  cos/sin table (1024 pos x 32 x {cos,sin})
#define OFF_XC     131072       // 5242880 modulated concat input (5120 x 1024)
#define OFF_QKV    5373952      // 15728640 qkv gemm out (5120 x 3072)
#define OFF_Q      21102592     // 5242880 Q (B,H,1280,64)
#define OFF_K      26345472     // 5242880
#define OFF_V      31588352     // 5242880
#define OFF_O      36831232     // 5242880 attn out (b,t,c) order
#define OFF_X1     42074112     // 5242880 post-resid1, pixel rows [0,4096) then dino [4096,5120)
#define OFF_MLPIN  47316992     // 5242880
#define OFF_H12    131072       // 27955200 (5120 x 5460) overlays xc/qkv/QKV

__device__ __forceinline__ float siluf(float x) { return x / (1.f + expf(-x)); }

__device__ __forceinline__ float blockReduceSum256(float v) {
  __shared__ float red[4];
  #pragma unroll
  for (int o = 32; o > 0; o >>= 1) v += __shfl_down(v, o);
  if ((threadIdx.x & 63) == 0) red[threadIdx.x >> 6] = v;
  __syncthreads();
  float r = red[0] + red[1] + red[2] + red[3];
  __syncthreads();
  return r;
}

// ---- silu(c) ----
__global__ void k_silu(const float* __restrict__ c, float* __restrict__ sc, int n) {
  int i = blockIdx.x * 256 + threadIdx.x;
  if (i < n) sc[i] = siluf(c[i]);
}

// ---- ada = silu(c) @ w_ada + b_ada  (M=4, K=1024, N=6144), y-dim picks p/d ----
__global__ __launch_bounds__(256) void k_ada(
    const float* __restrict__ sc,
    const float* __restrict__ wp, const float* __restrict__ bp,
    const float* __restrict__ wd, const float* __restrict__ bd,
    float* __restrict__ adap, float* __restrict__ adad) {
  __shared__ float s[BATCH * CDIM];
  const float* w   = blockIdx.y ? wd : wp;
  const float* bia = blockIdx.y ? bd : bp;
  float* out       = blockIdx.y ? adad : adap;
  int tid = threadIdx.x;
  for (int i = tid; i < BATCH * CDIM; i += 256) s[i] = sc[i];
  __syncthreads();
  int n = blockIdx.x * 256 + tid;
  float a0 = 0.f, a1 = 0.f, a2 = 0.f, a3 = 0.f;
  for (int k = 0; k < CDIM; k++) {
    float wv = w[(size_t)k * N6C + n];
    a0 += s[k] * wv;
    a1 += s[CDIM + k] * wv;
    a2 += s[2 * CDIM + k] * wv;
    a3 += s[3 * CDIM + k] * wv;
  }
  float bv = bia[n];
  out[0 * N6C + n] = a0 + bv;
  out[1 * N6C + n] = a1 + bv;
  out[2 * N6C + n] = a2 + bv;
  out[3 * N6C + n] = a3 + bv;
}

// ---- rope cos/sin table: tab[pos*64 + i] = cos, tab[pos*64+32+i] = sin ----
__global__ void k_ropetab(float* __restrict__ tab) {
  int pos = blockIdx.x;
  int i = threadIdx.x;
  if (i < 32) {
    float f = powf(10000.f, -2.f * (float)i / 64.f);
    float ang = (float)pos * f;
    tab[pos * 64 + i]      = cosf(ang);
    tab[pos * 64 + 32 + i] = sinf(ang);
  }
}

// ---- rms_norm(x, g_n1) then modulate with (sh_a, sc_a); writes xc in (b*1280+t) row order ----
__global__ __launch_bounds__(256) void k_rmsmod1(
    const float* __restrict__ xp, const float* __restrict__ xd,
    const float* __restrict__ adap, const float* __restrict__ adad,
    const float* __restrict__ g1p, const float* __restrict__ g1d,
    float* __restrict__ xc) {
  int r = blockIdx.x;           // b*1280 + t
  int b = r / NTOT, t = r % NTOT;
  bool pix = t < NP;
  const float* src = pix ? xp + ((size_t)b * NP + t) * CDIM
                         : xd + ((size_t)b * ND + (t - NP)) * CDIM;
  const float* ada = pix ? adap : adad;
  const float* g   = pix ? g1p : g1d;
  int tid = threadIdx.x;
  float vals[4];
  float ss = 0.f;
  #pragma unroll
  for (int i = 0; i < 4; i++) {
    float x = src[tid + i * 256];
    vals[i] = x;
    ss += x * x;
  }
  ss = blockReduceSum256(ss);
  float inv = 1.f / sqrtf(ss * (1.f / CDIM) + EPSF);
  float* dst = xc + (size_t)r * CDIM;
  #pragma unroll
  for (int i = 0; i < 4; i++) {
    int cx = tid + i * 256;
    float sh = ada[b * N6C + cx];
    float sl = ada[b * N6C + CDIM + cx];
    dst[cx] = vals[i] * inv * g[cx] * (1.f + sl) + sh;
  }
}

// ---- generic fp32 GEMM: out = A[M,K] @ W[K,N] + bias. M % 128 == 0 required. ----
__global__ __launch_bounds__(256) void k_gemm_bias(
    const float* __restrict__ A, const float* __restrict__ W,
    const float* __restrict__ bias, float* __restrict__ out,
    int M, int N, int K) {
  __shared__ float As[8][128];
  __shared__ float Ws[8][128];
  const int tid = threadIdx.x;
  const int bm = blockIdx.y * 128;
  const int bn = blockIdx.x * 128;
  const int arow = tid >> 1, acg = (tid & 1) * 4;
  const int wrow = tid >> 5, wcol = (tid & 31) * 4;
  const int tx = tid & 15, ty = tid >> 4;
  float acc[8][8];
  #pragma unroll
  for (int i = 0; i < 8; i++)
    #pragma unroll
    for (int j = 0; j < 8; j++) acc[i][j] = 0.f;

  for (int k0 = 0; k0 < K; k0 += 8) {
    {
      int ak = k0 + acg;
      const float* ap = A + (size_t)(bm + arow) * K + ak;
      float4 av;
      if (ak + 3 < K) av = *(const float4*)ap;
      else {
        av.x = (ak + 0 < K) ? ap[0] : 0.f;
        av.y = (ak + 1 < K) ? ap[1] : 0.f;
        av.z = (ak + 2 < K) ? ap[2] : 0.f;
        av.w = 0.f;
      }
      As[acg + 0][arow] = av.x;
      As[acg + 1][arow] = av.y;
      As[acg + 2][arow] = av.z;
      As[acg + 3][arow] = av.w;
    }
    {
      int wk = k0 + wrow;
      int wn = bn + wcol;
      float4 wv = make_float4(0.f, 0.f, 0.f, 0.f);
      if (wk < K) {
        const float* wp = W + (size_t)wk * N + wn;
        if (wn + 3 < N) wv = *(const float4*)wp;
        else {
          if (wn + 0 < N) wv.x = wp[0];
          if (wn + 1 < N) wv.y = wp[1];
          if (wn + 2 < N) wv.z = wp[2];
        }
      }
      *(float4*)&Ws[wrow][wcol] = wv;
    }
    __syncthreads();
    #pragma unroll
    for (int k = 0; k < 8; k++) {
      float a[8], w[8];
      *(float4*)&a[0] = *(float4*)&As[k][ty * 8];
      *(float4*)&a[4] = *(float4*)&As[k][ty * 8 + 4];
      *(float4*)&w[0] = *(float4*)&Ws[k][tx * 8];
      *(float4*)&w[4] = *(float4*)&Ws[k][tx * 8 + 4];
      #pragma unroll
      for (int i = 0; i < 8; i++)
        #pragma unroll
        for (int j = 0; j < 8; j++) acc[i][j] += a[i] * w[j];
    }
    __syncthreads();
  }
  #pragma unroll
  for (int i = 0; i < 8; i++) {
    int row = bm + ty * 8 + i;
    #pragma unroll
    for (int j = 0; j < 8; j++) {
      int col = bn + tx * 8 + j;
      if (col < N) out[(size_t)row * N + col] = acc[i][j] + bias[col];
    }
  }
}

// ---- qkv split: per-head rms_norm (q,k) + rope + transpose to (B,H,n,DH) ----
__global__ __launch_bounds__(256) void k_qkvsplit(
    const float* __restrict__ qkv, const float* __restrict__ gq,
    const float* __restrict__ gk, const float* __restrict__ tab,
    float* __restrict__ Q, float* __restrict__ K, float* __restrict__ V) {
  const int t = blockIdx.x, b = blockIdx.y;
  const int lane = threadIdx.x & 63;
  const int wv = threadIdx.x >> 6;
  const float* row = qkv + ((size_t)b * NTOT + t) * 3072;
  const int pos = (t < NP) ? t : (t - NP);
  const int fi = lane & 31;
  const float cs = tab[pos * 64 + fi];
  const float sn = tab[pos * 64 + 32 + fi];
  #pragma unroll
  for (int hg = 0; hg < 4; hg++) {
    const int h = hg * 4 + wv;
    const size_t oidx = (((size_t)b * NH + h) * NTOT + t) * DHD + lane;
    {
      float x = row[h * 64 + lane];
      float ss = x * x;
      #pragma unroll
      for (int o = 32; o > 0; o >>= 1) ss += __shfl_xor(ss, o);
      float xn = x * (1.f / sqrtf(ss * (1.f / 64.f) + EPSF)) * gq[lane];
      float p = __shfl_xor(xn, 32);
      Q[oidx] = (lane < 32) ? (xn * cs - p * sn) : (p * sn + xn * cs);
    }
    {
      float x = row[1024 + h * 64 + lane];
      float ss = x * x;
      #pragma unroll
      for (int o = 32; o > 0; o >>= 1) ss += __shfl_xor(ss, o);
      float xn = x * (1.f / sqrtf(ss * (1.f / 64.f) + EPSF)) * gk[lane];
      float p = __shfl_xor(xn, 32);
      K[oidx] = (lane < 32) ? (xn * cs - p * sn) : (p * sn + xn * cs);
    }
    V[oidx] = row[2048 + h * 64 + lane];
  }
}

// ---- flash attention fp32: 32 q-rows per block, 32-key tiles, online softmax ----
__global__ __launch_bounds__(256) void k_attn(
    const float* __restrict__ Q, const float* __restrict__ Kg,
    const float* __restrict__ V, const int* __restrict__ blk,
    float* __restrict__ O) {
  __shared__ float qs[32][64];
  __shared__ float ks[32][64];
  __shared__ float vs[32][64];
  const int bh = blockIdx.y;
  const int b = bh >> 4, h = bh & 15;
  const int q0 = blockIdx.x * 32;
  const float* Qb = Q + (size_t)bh * NTOT * DHD;
  const float* Kb = Kg + (size_t)bh * NTOT * DHD;
  const float* Vb = V + (size_t)bh * NTOT * DHD;
  const int tid = threadIdx.x;
  {
    const float4* src = (const float4*)(Qb + (size_t)q0 * DHD);
    float4* dst = (float4*)&qs[0][0];
    dst[tid] = src[tid];
    dst[tid + 256] = src[tid + 256];
  }
  const int r = tid >> 3, g = tid & 7;
  const int d0 = g * 8;
  float acc[8] = {0.f, 0.f, 0.f, 0.f, 0.f, 0.f, 0.f, 0.f};
  float mrow = -INFINITY, lrow = 0.f;
  const bool blocked_b = blk[b] != 0;
  const bool qpix = (q0 + r) < NP;
  const int gbase = (tid & 63) & ~7;

  for (int kb = 0; kb < NTOT; kb += 32) {
    __syncthreads();
    {
      const float4* ksrc = (const float4*)(Kb + (size_t)kb * DHD);
      const float4* vsrc = (const float4*)(Vb + (size_t)kb * DHD);
      float4* kd = (float4*)&ks[0][0];
      float4* vd = (float4*)&vs[0][0];
      kd[tid] = ksrc[tid];
      kd[tid + 256] = ksrc[tid + 256];
      vd[tid] = vsrc[tid];
      vd[tid + 256] = vsrc[tid + 256];
    }
    __syncthreads();
    float s[4];
    #pragma unroll
    for (int jj = 0; jj < 4; jj++) {
      int j = g * 4 + jj;
      float dot = 0.f;
      #pragma unroll
      for (int d = 0; d < 64; d += 4) {
        float4 qv = *(float4*)&qs[r][d];
        float4 kv = *(float4*)&ks[j][d];
        dot += qv.x * kv.x + qv.y * kv.y + qv.z * kv.z + qv.w * kv.w;
      }
      s[jj] = dot * 0.125f;
      if (blocked_b && qpix && (kb + j >= NP)) s[jj] = -INFINITY;
    }
    float pm = fmaxf(fmaxf(s[0], s[1]), fmaxf(s[2], s[3]));
    pm = fmaxf(pm, __shfl_xor(pm, 1));
    pm = fmaxf(pm, __shfl_xor(pm, 2));
    pm = fmaxf(pm, __shfl_xor(pm, 4));
    float mn = fmaxf(mrow, pm);              // finite from first tile (keys 0..31 never blocked)
    float corr = expf(mrow - mn);            // first iter: exp(-inf) = 0
    float p[4];
    float ls = 0.f;
    #pragma unroll
    for (int jj = 0; jj < 4; jj++) { p[jj] = expf(s[jj] - mn); ls += p[jj]; }
    ls += __shfl_xor(ls, 1);
    ls += __shfl_xor(ls, 2);
    ls += __shfl_xor(ls, 4);
    lrow = lrow * corr + ls;
    mrow = mn;
    #pragma unroll
    for (int d = 0; d < 8; d++) acc[d] *= corr;
    #pragma unroll
    for (int gp = 0; gp < 8; gp++) {
      float pb0 = __shfl(p[0], gbase + gp);
      float pb1 = __shfl(p[1], gbase + gp);
      float pb2 = __shfl(p[2], gbase + gp);
      float pb3 = __shfl(p[3], gbase + gp);
      #pragma unroll
      for (int jj = 0; jj < 4; jj++) {
        int j = gp * 4 + jj;
        float pj = (jj == 0) ? pb0 : (jj == 1) ? pb1 : (jj == 2) ? pb2 : pb3;
        float4 v0 = *(float4*)&vs[j][d0];
        float4 v1 = *(float4*)&vs[j][d0 + 4];
        acc[0] += pj * v0.x; acc[1] += pj * v0.y;
        acc[2] += pj * v0.z; acc[3] += pj * v0.w;
        acc[4] += pj * v1.x; acc[5] += pj * v1.y;
        acc[6] += pj * v1.z; acc[7] += pj * v1.w;
      }
    }
  }
  float invl = 1.f / lrow;
  float* orow = O + ((size_t)(b * NTOT + q0 + r)) * CDIM + h * 64 + d0;
  #pragma unroll
  for (int d = 0; d < 8; d++) orow[d] = acc[d] * invl;
}

// ---- proj GEMM fused with resid1: x1 = x_in + g_a * (O @ w_proj + b) ----
// M=5120 (b*1280+t order), N=K=1024. Writes x1 in [pixel 0..4096 | dino 4096..5120] layout.
__global__ __launch_bounds__(256) void k_gemm_proj(
    const float* __restrict__ A, const float* __restrict__ W,
    const float* __restrict__ bias,
    const float* __restrict__ xp, const float* __restrict__ xd,
    const float* __restrict__ adap, const float* __restrict__ adad,
    float* __restrict__ x1) {
  __shared__ float As[8][128];
  __shared__ float Ws[8][128];
  const int tid = threadIdx.x;
  const int bm = blockIdx.y * 128;
  const int bn = blockIdx.x * 128;
  const int arow = tid >> 1, acg = (tid & 1) * 4;
  const int wrow = tid >> 5, wcol = (tid & 31) * 4;
  const int tx = tid & 15, ty = tid >> 4;
  float acc[8][8];
  #pragma unroll
  for (int i = 0; i < 8; i++)
    #pragma unroll
    for (int j = 0; j < 8; j++) acc[i][j] = 0.f;

  for (int k0 = 0; k0 < 1024; k0 += 8) {
    {
      const float* ap = A + (size_t)(bm + arow) * 1024 + k0 + acg;
      float4 av = *(const float4*)ap;
      As[acg + 0][arow] = av.x;
      As[acg + 1][arow] = av.y;
      As[acg + 2][arow] = av.z;
      As[acg + 3][arow] = av.w;
    }
    {
      const float* wp = W + (size_t)(k0 + wrow) * 1024 + bn + wcol;
      *(float4*)&Ws[wrow][wcol] = *(const float4*)wp;
    }
    __syncthreads();
    #pragma unroll
    for (int k = 0; k < 8; k++) {
      float a[8], w[8];
      *(float4*)&a[0] = *(float4*)&As[k][ty * 8];
      *(float4*)&a[4] = *(float4*)&As[k][ty * 8 + 4];
      *(float4*)&w[0] = *(float4*)&Ws[k][tx * 8];
      *(float4*)&w[4] = *(float4*)&Ws[k][tx * 8 + 4];
      #pragma unroll
      for (int i = 0; i < 8; i++)
        #pragma unroll
        for (int j = 0; j < 8; j++) acc[i][j] += a[i] * w[j];
    }
    __syncthreads();
  }
  #pragma unroll
  for (int i = 0; i < 8; i++) {
    int row = bm + ty * 8 + i;
    int b = row / NTOT, t = row % NTOT;
    #pragma unroll
    for (int j = 0; j < 8; j++) {
      int col = bn + tx * 8 + j;
      float v = acc[i][j] + bias[col];
      if (t < NP) {
        float ga = adap[b * N6C + 2 * CDIM + col];
        float xin = xp[((size_t)b * NP + t) * CDIM + col];
        x1[((size_t)(b * NP + t)) * CDIM + col] = xin + ga * v;
      } else {
        int td = t - NP;
        float ga = adad[b * N6C + 2 * CDIM + col];
        float xin = xd[((size_t)b * ND + td) * CDIM + col];
        x1[((size_t)(4096 + b * ND + td)) * CDIM + col] = xin + ga * v;
      }
    }
  }
}

// ---- second norm+modulate on x1 rows (pixel-first layout) ----
__global__ __launch_bounds__(256) void k_rmsmod2(
    const float* __restrict__ x1,
    const float* __restrict__ adap, const float* __restrict__ adad,
    const float* __restrict__ g2p, const float* __restrict__ g2d,
    float* __restrict__ mlpin) {
  int r = blockIdx.x;
  bool pix = r < 4096;
  int b = pix ? (r >> 10) : ((r - 4096) >> 8);
  const float* ada = pix ? adap : adad;
  const float* g   = pix ? g2p : g2d;
  const float* src = x1 + (size_t)r * CDIM;
  int tid = threadIdx.x;
  float vals[4];
  float ss = 0.f;
  #pragma unroll
  for (int i = 0; i < 4; i++) {
    float x = src[tid + i * 256];
    vals[i] = x;
    ss += x * x;
  }
  ss = blockReduceSum256(ss);
  float inv = 1.f / sqrtf(ss * (1.f / CDIM) + EPSF);
  float* dst = mlpin + (size_t)r * CDIM;
  #pragma unroll
  for (int i = 0; i < 4; i++) {
    int cx = tid + i * 256;
    float sh = ada[b * N6C + 3 * CDIM + cx];
    float sl = ada[b * N6C + 4 * CDIM + cx];
    dst[cx] = vals[i] * inv * g[cx] * (1.f + sl) + sh;
  }
}

// ---- mlp2: A[m][k] = silu(h12[m][k]) * h12[m][k+HID]; out = x1 + g_m*(A@w3 + b3) -> d_out ----
// K = 2730, N = 1024, M % 128 == 0 (grid covers M exactly).
__global__ __launch_bounds__(256) void k_gemm_mlp2(
    const float* __restrict__ h12b, const float* __restrict__ W,
    const float* __restrict__ bias, const float* __restrict__ x1b,
    const float* __restrict__ ada, float* __restrict__ outb,
    int rows_per_batch) {
  __shared__ float As[8][128];
  __shared__ float Ws[8][128];
  const int tid = threadIdx.x;
  const int bm = blockIdx.y * 128;
  const int bn = blockIdx.x * 128;
  const int arow = tid >> 1, acg = (tid & 1) * 4;
  const int wrow = tid >> 5, wcol = (tid & 31) * 4;
  const int tx = tid & 15, ty = tid >> 4;
  float acc[8][8];
  #pragma unroll
  for (int i = 0; i < 8; i++)
    #pragma unroll
    for (int j = 0; j < 8; j++) acc[i][j] = 0.f;

  for (int k0 = 0; k0 < HID; k0 += 8) {
    {
      int ak = k0 + acg;
      const float* hrow = h12b + (size_t)(bm + arow) * N12;
      float a0 = 0.f, a1 = 0.f, a2 = 0.f, a3 = 0.f;
      if (ak + 3 < HID) {
        float4 h1 = *(const float4*)(hrow + ak);
        // HID=2730 is not a multiple of 4 -> the x2 half is only 8B-aligned
        float2 h2a = *(const float2*)(hrow + HID + ak);
        float2 h2b = *(const float2*)(hrow + HID + ak + 2);
        a0 = siluf(h1.x) * h2a.x;
        a1 = siluf(h1.y) * h2a.y;
        a2 = siluf(h1.z) * h2b.x;
        a3 = siluf(h1.w) * h2b.y;
      } else {
        if (ak + 0 < HID) a0 = siluf(hrow[ak + 0]) * hrow[HID + ak + 0];
        if (ak + 1 < HID) a1 = siluf(hrow[ak + 1]) * hrow[HID + ak + 1];
        if (ak + 2 < HID) a2 = siluf(hrow[ak + 2]) * hrow[HID + ak + 2];
      }
      As[acg + 0][arow] = a0;
      As[acg + 1][arow] = a1;
      As[acg + 2][arow] = a2;
      As[acg + 3][arow] = a3;
    }
    {
      int wk = k0 + wrow;
      float4 wv = make_float4(0.f, 0.f, 0.f, 0.f);
      if (wk < HID) wv = *(const float4*)(W + (size_t)wk * CDIM + bn + wcol);
      *(float4*)&Ws[wrow][wcol] = wv;
    }
    __syncthreads();
    #pragma unroll
    for (int k = 0; k < 8; k++) {
      float a[8], w[8];
      *(float4*)&a[0] = *(float4*)&As[k][ty * 8];
      *(float4*)&a[4] = *(float4*)&As[k][ty * 8 + 4];
      *(float4*)&w[0] = *(float4*)&Ws[k][tx * 8];
      *(float4*)&w[4] = *(float4*)&Ws[k][tx * 8 + 4];
      #pragma unroll
      for (int i = 0; i < 8; i++)
        #pragma unroll
        for (int j = 0; j < 8; j++) acc[i][j] += a[i] * w[j];
    }
    __syncthreads();
  }
  #pragma unroll
  for (int i = 0; i < 8; i++) {
    int row = bm + ty * 8 + i;
    int b = row / rows_per_batch;
    #pragma unroll
    for (int j = 0; j < 8; j++) {
      int col = bn + tx * 8 + j;
      float gm = ada[b * N6C + 5 * CDIM + col];
      float v = acc[i][j] + bias[col];
      outb[(size_t)row * CDIM + col] = x1b[(size_t)row * CDIM + col] + gm * v;
    }
  }
}

extern "C" void kernel_launch(void* const* d_in, const int* in_sizes, int n_in,
                              void* d_out, int out_size, void* d_ws, size_t ws_size,
                              hipStream_t stream) {
  const float* x_pixel = (const float*)d_in[0];
  const float* x_dino  = (const float*)d_in[1];
  const float* c       = (const float*)d_in[2];
  const float* w_ada_p = (const float*)d_in[3];
  const float* b_ada_p = (const float*)d_in[4];
  const float* w_ada_d = (const float*)d_in[5];
  const float* b_ada_d = (const float*)d_in[6];
  const float* g_n1p   = (const float*)d_in[7];
  const float* g_n1d   = (const float*)d_in[8];
  const float* g_n2p   = (const float*)d_in[9];
  const float* g_n2d   = (const float*)d_in[10];
  const float* w_qkv   = (const float*)d_in[11];
  const float* b_qkv   = (const float*)d_in[12];
  const float* g_qn    = (const float*)d_in[13];
  const float* g_kn    = (const float*)d_in[14];
  const float* w_proj  = (const float*)d_in[15];
  const float* b_proj  = (const float*)d_in[16];
  const float* w12_p   = (const float*)d_in[17];
  const float* b12_p   = (const float*)d_in[18];
  const float* w3_p    = (const float*)d_in[19];
  const float* b3_p    = (const float*)d_in[20];
  const float* w12_d   = (const float*)d_in[21];
  const float* b12_d   = (const float*)d_in[22];
  const float* w3_d    = (const float*)d_in[23];
  const float* b3_d    = (const float*)d_in[24];
  const int*   blk     = (const int*)d_in[25];
  float* out = (float*)d_out;
  float* ws  = (float*)d_ws;

  float* sc    = ws + OFF_SC;
  float* ada_p = ws + OFF_ADAP;
  float* ada_d = ws + OFF_ADAD;
  float* rope  = ws + OFF_ROPE;
  float* xc    = ws + OFF_XC;
  float* qkv   = ws + OFF_QKV;
  float* Qb    = ws + OFF_Q;
  float* Kb    = ws + OFF_K;
  float* Vb    = ws + OFF_V;
  float* Ob    = ws + OFF_O;
  float* x1    = ws + OFF_X1;
  float* mlpin = ws + OFF_MLPIN;
  float* h12   = ws + OFF_H12;

  hipLaunchKernelGGL(k_silu, dim3(16), dim3(256), 0, stream, c, sc, BATCH * CDIM);
  hipLaunchKernelGGL(k_ada, dim3(24, 2), dim3(256), 0, stream,
                     sc, w_ada_p, b_ada_p, w_ada_d, b_ada_d, ada_p, ada_d);
  hipLaunchKernelGGL(k_ropetab, dim3(NP), dim3(64), 0, stream, rope);
  hipLaunchKernelGGL(k_rmsmod1, dim3(BATCH * NTOT), dim3(256), 0, stream,
                     x_pixel, x_dino, ada_p, ada_d, g_n1p, g_n1d, xc);
  hipLaunchKernelGGL(k_gemm_bias, dim3(3072 / 128, 5120 / 128), dim3(256), 0, stream,
                     xc, w_qkv, b_qkv, qkv, 5120, 3072, 1024);
  hipLaunchKernelGGL(k_qkvsplit, dim3(NTOT, BATCH), dim3(256), 0, stream,
                     qkv, g_qn, g_kn, rope, Qb, Kb, Vb);
  hipLaunchKernelGGL(k_attn, dim3(NTOT / 32, BATCH * NH), dim3(256), 0, stream,
                     Qb, Kb, Vb, blk, Ob);
  hipLaunchKernelGGL(k_gemm_proj, dim3(1024 / 128, 5120 / 128), dim3(256), 0, stream,
                     Ob, w_proj, b_proj, x_pixel, x_dino, ada_p, ada_d, x1);
  hipLaunchKernelGGL(k_rmsmod2, dim3(5120), dim3(256), 0, stream,
                     x1, ada_p, ada_d, g_n2p, g_n2d, mlpin);
  hipLaunchKernelGGL(k_gemm_bias, dim3(43, 4096 / 128), dim3(256), 0, stream,
                     mlpin, w12_p, b12_p, h12, 4096, N12, 1024);
  hipLaunchKernelGGL(k_gemm_bias, dim3(43, 1024 / 128), dim3(256), 0, stream,
                     mlpin + (size_t)4096 * CDIM, w12_d, b12_d,
                     h12 + (size_t)4096 * N12, 1024, N12, 1024);
  hipLaunchKernelGGL(k_gemm_mlp2, dim3(1024 / 128, 4096 / 128), dim3(256), 0, stream,
                     h12, w3_p, b3_p, x1, ada_p, out, 1024);
  hipLaunchKernelGGL(k_gemm_mlp2, dim3(1024 / 128, 1024 / 128), dim3(256), 0, stream,
                     h12 + (size_t)4096 * N12, w3_d, b3_d, x1 + (size_t)4096 * CDIM,
                     ada_d, out + (size_t)BATCH * NP * CDIM, 256);
}

// Round 2
// 3848.480 us; speedup vs baseline: 1.3151x; 1.3151x over previous
//
#include <hip/hip_runtime.h>
#include <math.h>

// ---- problem dims ----
#define BATCH 4
#define NP 1024
#define ND 256
#define NTOT 1280
#define CDIM 1024
#define NH 16
#define DHD 64
#define HID 2730
#define N12 5460
#define N6C 6144
#define EPSF 1e-6f

// ---- workspace layout (float offsets). Total 52,559,872 floats = 210 MB ----
#define OFF_SC     0
#define OFF_ADAP   4096
#define OFF_ADAD   28672
#define OFF_ROPE   53248
#define OFF_XC     131072
#define OFF_QKV    5373952
#define OFF_Q      21102592
#define OFF_K      26345472
#define OFF_V      31588352
#define OFF_O      36831232
#define OFF_X1     42074112
#define OFF_MLPIN  47316992
#define OFF_H12    131072

__device__ __forceinline__ float siluf(float x) { return x / (1.f + expf(-x)); }

__device__ __forceinline__ float blockReduceSum256(float v) {
  __shared__ float red[4];
  #pragma unroll
  for (int o = 32; o > 0; o >>= 1) v += __shfl_down(v, o);
  if ((threadIdx.x & 63) == 0) red[threadIdx.x >> 6] = v;
  __syncthreads();
  float r = red[0] + red[1] + red[2] + red[3];
  __syncthreads();
  return r;
}

__global__ void k_silu(const float* __restrict__ c, float* __restrict__ sc, int n) {
  int i = blockIdx.x * 256 + threadIdx.x;
  if (i < n) sc[i] = siluf(c[i]);
}

__global__ __launch_bounds__(256) void k_ada(
    const float* __restrict__ sc,
    const float* __restrict__ wp, const float* __restrict__ bp,
    const float* __restrict__ wd, const float* __restrict__ bd,
    float* __restrict__ adap, float* __restrict__ adad) {
  __shared__ float s[BATCH * CDIM];
  const float* w   = blockIdx.y ? wd : wp;
  const float* bia = blockIdx.y ? bd : bp;
  float* out       = blockIdx.y ? adad : adap;
  int tid = threadIdx.x;
  for (int i = tid; i < BATCH * CDIM; i += 256) s[i] = sc[i];
  __syncthreads();
  int n = blockIdx.x * 256 + tid;
  float a0 = 0.f, a1 = 0.f, a2 = 0.f, a3 = 0.f;
  for (int k = 0; k < CDIM; k++) {
    float wv = w[(size_t)k * N6C + n];
    a0 += s[k] * wv;
    a1 += s[CDIM + k] * wv;
    a2 += s[2 * CDIM + k] * wv;
    a3 += s[3 * CDIM + k] * wv;
  }
  float bv = bia[n];
  out[0 * N6C + n] = a0 + bv;
  out[1 * N6C + n] = a1 + bv;
  out[2 * N6C + n] = a2 + bv;
  out[3 * N6C + n] = a3 + bv;
}

__global__ void k_ropetab(float* __restrict__ tab) {
  int pos = blockIdx.x;
  int i = threadIdx.x;
  if (i < 32) {
    float f = powf(10000.f, -2.f * (float)i / 64.f);
    float ang = (float)pos * f;
    tab[pos * 64 + i]      = cosf(ang);
    tab[pos * 64 + 32 + i] = sinf(ang);
  }
}

__global__ __launch_bounds__(256) void k_rmsmod1(
    const float* __restrict__ xp, const float* __restrict__ xd,
    const float* __restrict__ adap, const float* __restrict__ adad,
    const float* __restrict__ g1p, const float* __restrict__ g1d,
    float* __restrict__ xc) {
  int r = blockIdx.x;
  int b = r / NTOT, t = r % NTOT;
  bool pix = t < NP;
  const float* src = pix ? xp + ((size_t)b * NP + t) * CDIM
                         : xd + ((size_t)b * ND + (t - NP)) * CDIM;
  const float* ada = pix ? adap : adad;
  const float* g   = pix ? g1p : g1d;
  int tid = threadIdx.x;
  float vals[4];
  float ss = 0.f;
  #pragma unroll
  for (int i = 0; i < 4; i++) {
    float x = src[tid + i * 256];
    vals[i] = x;
    ss += x * x;
  }
  ss = blockReduceSum256(ss);
  float inv = 1.f / sqrtf(ss * (1.f / CDIM) + EPSF);
  float* dst = xc + (size_t)r * CDIM;
  #pragma unroll
  for (int i = 0; i < 4; i++) {
    int cx = tid + i * 256;
    float sh = ada[b * N6C + cx];
    float sl = ada[b * N6C + CDIM + cx];
    dst[cx] = vals[i] * inv * g[cx] * (1.f + sl) + sh;
  }
}

// ---- generic fp32 GEMM: out = A[M,K] @ W[K,N] + bias. M % 128 == 0 required. ----
// Microtile split-column mapping: thread covers cols {tx*4..+3} and {64+tx*4..+3}
// (2-way LDS aliasing = free, vs 4-way at tx*8), rows {ty*4..} and {64+ty*4..}.
__global__ __launch_bounds__(256) void k_gemm_bias(
    const float* __restrict__ A, const float* __restrict__ W,
    const float* __restrict__ bias, float* __restrict__ out,
    int M, int N, int K) {
  __shared__ float As[8][128];
  __shared__ float Ws[8][128];
  const int tid = threadIdx.x;
  const int bm = blockIdx.y * 128;
  const int bn = blockIdx.x * 128;
  const int arow = tid >> 1, acg = (tid & 1) * 4;
  const int wrow = tid >> 5, wcol = (tid & 31) * 4;
  const int tx = tid & 15, ty = tid >> 4;
  float acc[8][8];
  #pragma unroll
  for (int i = 0; i < 8; i++)
    #pragma unroll
    for (int j = 0; j < 8; j++) acc[i][j] = 0.f;

  for (int k0 = 0; k0 < K; k0 += 8) {
    {
      int ak = k0 + acg;
      const float* ap = A + (size_t)(bm + arow) * K + ak;
      float4 av;
      if (ak + 3 < K) av = *(const float4*)ap;
      else {
        av.x = (ak + 0 < K) ? ap[0] : 0.f;
        av.y = (ak + 1 < K) ? ap[1] : 0.f;
        av.z = (ak + 2 < K) ? ap[2] : 0.f;
        av.w = 0.f;
      }
      As[acg + 0][arow] = av.x;
      As[acg + 1][arow] = av.y;
      As[acg + 2][arow] = av.z;
      As[acg + 3][arow] = av.w;
    }
    {
      int wk = k0 + wrow;
      int wn = bn + wcol;
      float4 wv = make_float4(0.f, 0.f, 0.f, 0.f);
      if (wk < K) {
        const float* wp = W + (size_t)wk * N + wn;
        if (wn + 3 < N) wv = *(const float4*)wp;
        else {
          if (wn + 0 < N) wv.x = wp[0];
          if (wn + 1 < N) wv.y = wp[1];
          if (wn + 2 < N) wv.z = wp[2];
        }
      }
      *(float4*)&Ws[wrow][wcol] = wv;
    }
    __syncthreads();
    #pragma unroll
    for (int k = 0; k < 8; k++) {
      float a[8], w[8];
      *(float4*)&a[0] = *(float4*)&As[k][ty * 4];
      *(float4*)&a[4] = *(float4*)&As[k][64 + ty * 4];
      *(float4*)&w[0] = *(float4*)&Ws[k][tx * 4];
      *(float4*)&w[4] = *(float4*)&Ws[k][64 + tx * 4];
      #pragma unroll
      for (int i = 0; i < 8; i++)
        #pragma unroll
        for (int j = 0; j < 8; j++) acc[i][j] += a[i] * w[j];
    }
    __syncthreads();
  }
  #pragma unroll
  for (int i = 0; i < 8; i++) {
    int row = bm + ((i < 4) ? ty * 4 + i : 64 + ty * 4 + (i - 4));
    #pragma unroll
    for (int h = 0; h < 2; h++) {
      int col = bn + h * 64 + tx * 4;
      if (col + 3 < N) {
        float4 bv = *(const float4*)&bias[col];
        float4 o;
        o.x = acc[i][h * 4 + 0] + bv.x;
        o.y = acc[i][h * 4 + 1] + bv.y;
        o.z = acc[i][h * 4 + 2] + bv.z;
        o.w = acc[i][h * 4 + 3] + bv.w;
        *(float4*)&out[(size_t)row * N + col] = o;
      } else {
        #pragma unroll
        for (int j = 0; j < 4; j++)
          if (col + j < N)
            out[(size_t)row * N + col + j] = acc[i][h * 4 + j] + bias[col + j];
      }
    }
  }
}

__global__ __launch_bounds__(256) void k_qkvsplit(
    const float* __restrict__ qkv, const float* __restrict__ gq,
    const float* __restrict__ gk, const float* __restrict__ tab,
    float* __restrict__ Q, float* __restrict__ K, float* __restrict__ V) {
  const int t = blockIdx.x, b = blockIdx.y;
  const int lane = threadIdx.x & 63;
  const int wv = threadIdx.x >> 6;
  const float* row = qkv + ((size_t)b * NTOT + t) * 3072;
  const int pos = (t < NP) ? t : (t - NP);
  const int fi = lane & 31;
  const float cs = tab[pos * 64 + fi];
  const float sn = tab[pos * 64 + 32 + fi];
  #pragma unroll
  for (int hg = 0; hg < 4; hg++) {
    const int h = hg * 4 + wv;
    const size_t oidx = (((size_t)b * NH + h) * NTOT + t) * DHD + lane;
    {
      float x = row[h * 64 + lane];
      float ss = x * x;
      #pragma unroll
      for (int o = 32; o > 0; o >>= 1) ss += __shfl_xor(ss, o);
      float xn = x * (1.f / sqrtf(ss * (1.f / 64.f) + EPSF)) * gq[lane];
      float p = __shfl_xor(xn, 32);
      Q[oidx] = (lane < 32) ? (xn * cs - p * sn) : (p * sn + xn * cs);
    }
    {
      float x = row[1024 + h * 64 + lane];
      float ss = x * x;
      #pragma unroll
      for (int o = 32; o > 0; o >>= 1) ss += __shfl_xor(ss, o);
      float xn = x * (1.f / sqrtf(ss * (1.f / 64.f) + EPSF)) * gk[lane];
      float p = __shfl_xor(xn, 32);
      K[oidx] = (lane < 32) ? (xn * cs - p * sn) : (p * sn + xn * cs);
    }
    V[oidx] = row[2048 + h * 64 + lane];
  }
}

// ---- flash attention fp32, bank-conflict-free LDS ----
// Rows padded to 68 floats (bank shift 4/row). Lane (r=tid>>3, g=tid&7)
// computes scores for keys j = jj*8+g (8 CONSECUTIVE ks rows per wave read
// -> 8 distinct banks; qs rows r=0..7 consecutive -> distinct banks).
#define LROW 68
__global__ __launch_bounds__(256) void k_attn(
    const float* __restrict__ Q, const float* __restrict__ Kg,
    const float* __restrict__ V, const int* __restrict__ blk,
    float* __restrict__ O) {
  __shared__ float qs[32][LROW];
  __shared__ float ks[32][LROW];
  __shared__ float vs[32][LROW];
  const int bh = blockIdx.y;
  const int b = bh >> 4, h = bh & 15;
  const int q0 = blockIdx.x * 32;
  const float* Qb = Q + (size_t)bh * NTOT * DHD;
  const float* Kb = Kg + (size_t)bh * NTOT * DHD;
  const float* Vb = V + (size_t)bh * NTOT * DHD;
  const int tid = threadIdx.x;
  {
    const float4* src = (const float4*)(Qb + (size_t)q0 * DHD);
    #pragma unroll
    for (int i = 0; i < 2; i++) {
      int e = tid + i * 256;
      int row = e >> 4, c4 = e & 15;
      ((float4*)qs)[row * (LROW / 4) + c4] = src[e];
    }
  }
  const int r = tid >> 3, g = tid & 7;
  const int d0 = g * 8;
  float acc[8] = {0.f, 0.f, 0.f, 0.f, 0.f, 0.f, 0.f, 0.f};
  float mrow = -INFINITY, lrow = 0.f;
  const bool blocked_b = blk[b] != 0;
  const bool qpix = (q0 + r) < NP;
  const int gbase = (tid & 63) & ~7;

  for (int kb = 0; kb < NTOT; kb += 32) {
    __syncthreads();
    {
      const float4* ksrc = (const float4*)(Kb + (size_t)kb * DHD);
      const float4* vsrc = (const float4*)(Vb + (size_t)kb * DHD);
      #pragma unroll
      for (int i = 0; i < 2; i++) {
        int e = tid + i * 256;
        int row = e >> 4, c4 = e & 15;
        ((float4*)ks)[row * (LROW / 4) + c4] = ksrc[e];
        ((float4*)vs)[row * (LROW / 4) + c4] = vsrc[e];
      }
    }
    __syncthreads();
    float s[4];
    #pragma unroll
    for (int jj = 0; jj < 4; jj++) {
      int j = jj * 8 + g;
      float dot = 0.f;
      #pragma unroll
      for (int d = 0; d < 64; d += 4) {
        float4 qv = *(float4*)&qs[r][d];
        float4 kv = *(float4*)&ks[j][d];
        dot += qv.x * kv.x + qv.y * kv.y + qv.z * kv.z + qv.w * kv.w;
      }
      s[jj] = dot * 0.125f;
      if (blocked_b && qpix && (kb + j >= NP)) s[jj] = -INFINITY;
    }
    float pm = fmaxf(fmaxf(s[0], s[1]), fmaxf(s[2], s[3]));
    pm = fmaxf(pm, __shfl_xor(pm, 1));
    pm = fmaxf(pm, __shfl_xor(pm, 2));
    pm = fmaxf(pm, __shfl_xor(pm, 4));
    float mn = fmaxf(mrow, pm);
    float corr = expf(mrow - mn);
    float p[4];
    float ls = 0.f;
    #pragma unroll
    for (int jj = 0; jj < 4; jj++) { p[jj] = expf(s[jj] - mn); ls += p[jj]; }
    ls += __shfl_xor(ls, 1);
    ls += __shfl_xor(ls, 2);
    ls += __shfl_xor(ls, 4);
    lrow = lrow * corr + ls;
    mrow = mn;
    #pragma unroll
    for (int d = 0; d < 8; d++) acc[d] *= corr;
    #pragma unroll
    for (int jj = 0; jj < 4; jj++) {
      #pragma unroll
      for (int gp = 0; gp < 8; gp++) {
        float pj = __shfl(p[jj], gbase + gp);
        int j = jj * 8 + gp;
        float4 v0 = *(float4*)&vs[j][d0];
        float4 v1 = *(float4*)&vs[j][d0 + 4];
        acc[0] += pj * v0.x; acc[1] += pj * v0.y;
        acc[2] += pj * v0.z; acc[3] += pj * v0.w;
        acc[4] += pj * v1.x; acc[5] += pj * v1.y;
        acc[6] += pj * v1.z; acc[7] += pj * v1.w;
      }
    }
  }
  float invl = 1.f / lrow;
  float* orow = O + ((size_t)(b * NTOT + q0 + r)) * CDIM + h * 64 + d0;
  #pragma unroll
  for (int d = 0; d < 8; d++) orow[d] = acc[d] * invl;
}

// ---- proj GEMM fused with resid1 ----
__global__ __launch_bounds__(256) void k_gemm_proj(
    const float* __restrict__ A, const float* __restrict__ W,
    const float* __restrict__ bias,
    const float* __restrict__ xp, const float* __restrict__ xd,
    const float* __restrict__ adap, const float* __restrict__ adad,
    float* __restrict__ x1) {
  __shared__ float As[8][128];
  __shared__ float Ws[8][128];
  const int tid = threadIdx.x;
  const int bm = blockIdx.y * 128;
  const int bn = blockIdx.x * 128;
  const int arow = tid >> 1, acg = (tid & 1) * 4;
  const int wrow = tid >> 5, wcol = (tid & 31) * 4;
  const int tx = tid & 15, ty = tid >> 4;
  float acc[8][8];
  #pragma unroll
  for (int i = 0; i < 8; i++)
    #pragma unroll
    for (int j = 0; j < 8; j++) acc[i][j] = 0.f;

  for (int k0 = 0; k0 < 1024; k0 += 8) {
    {
      const float* ap = A + (size_t)(bm + arow) * 1024 + k0 + acg;
      float4 av = *(const float4*)ap;
      As[acg + 0][arow] = av.x;
      As[acg + 1][arow] = av.y;
      As[acg + 2][arow] = av.z;
      As[acg + 3][arow] = av.w;
    }
    {
      const float* wp = W + (size_t)(k0 + wrow) * 1024 + bn + wcol;
      *(float4*)&Ws[wrow][wcol] = *(const float4*)wp;
    }
    __syncthreads();
    #pragma unroll
    for (int k = 0; k < 8; k++) {
      float a[8], w[8];
      *(float4*)&a[0] = *(float4*)&As[k][ty * 4];
      *(float4*)&a[4] = *(float4*)&As[k][64 + ty * 4];
      *(float4*)&w[0] = *(float4*)&Ws[k][tx * 4];
      *(float4*)&w[4] = *(float4*)&Ws[k][64 + tx * 4];
      #pragma unroll
      for (int i = 0; i < 8; i++)
        #pragma unroll
        for (int j = 0; j < 8; j++) acc[i][j] += a[i] * w[j];
    }
    __syncthreads();
  }
  #pragma unroll
  for (int i = 0; i < 8; i++) {
    int row = bm + ((i < 4) ? ty * 4 + i : 64 + ty * 4 + (i - 4));
    int b = row / NTOT, t = row % NTOT;
    #pragma unroll
    for (int h = 0; h < 2; h++) {
      int col = bn + h * 64 + tx * 4;
      float4 bv = *(const float4*)&bias[col];
      float4 v;
      v.x = acc[i][h * 4 + 0] + bv.x;
      v.y = acc[i][h * 4 + 1] + bv.y;
      v.z = acc[i][h * 4 + 2] + bv.z;
      v.w = acc[i][h * 4 + 3] + bv.w;
      if (t < NP) {
        float4 ga  = *(const float4*)&adap[b * N6C + 2 * CDIM + col];
        float4 xin = *(const float4*)&xp[((size_t)b * NP + t) * CDIM + col];
        float4 o;
        o.x = xin.x + ga.x * v.x; o.y = xin.y + ga.y * v.y;
        o.z = xin.z + ga.z * v.z; o.w = xin.w + ga.w * v.w;
        *(float4*)&x1[((size_t)(b * NP + t)) * CDIM + col] = o;
      } else {
        int td = t - NP;
        float4 ga  = *(const float4*)&adad[b * N6C + 2 * CDIM + col];
        float4 xin = *(const float4*)&xd[((size_t)b * ND + td) * CDIM + col];
        float4 o;
        o.x = xin.x + ga.x * v.x; o.y = xin.y + ga.y * v.y;
        o.z = xin.z + ga.z * v.z; o.w = xin.w + ga.w * v.w;
        *(float4*)&x1[((size_t)(4096 + b * ND + td)) * CDIM + col] = o;
      }
    }
  }
}

__global__ __launch_bounds__(256) void k_rmsmod2(
    const float* __restrict__ x1,
    const float* __restrict__ adap, const float* __restrict__ adad,
    const float* __restrict__ g2p, const float* __restrict__ g2d,
    float* __restrict__ mlpin) {
  int r = blockIdx.x;
  bool pix = r < 4096;
  int b = pix ? (r >> 10) : ((r - 4096) >> 8);
  const float* ada = pix ? adap : adad;
  const float* g   = pix ? g2p : g2d;
  const float* src = x1 + (size_t)r * CDIM;
  int tid = threadIdx.x;
  float vals[4];
  float ss = 0.f;
  #pragma unroll
  for (int i = 0; i < 4; i++) {
    float x = src[tid + i * 256];
    vals[i] = x;
    ss += x * x;
  }
  ss = blockReduceSum256(ss);
  float inv = 1.f / sqrtf(ss * (1.f / CDIM) + EPSF);
  float* dst = mlpin + (size_t)r * CDIM;
  #pragma unroll
  for (int i = 0; i < 4; i++) {
    int cx = tid + i * 256;
    float sh = ada[b * N6C + 3 * CDIM + cx];
    float sl = ada[b * N6C + 4 * CDIM + cx];
    dst[cx] = vals[i] * inv * g[cx] * (1.f + sl) + sh;
  }
}

// ---- mlp2 fused with swiglu gate + resid2 ----
__global__ __launch_bounds__(256) void k_gemm_mlp2(
    const float* __restrict__ h12b, const float* __restrict__ W,
    const float* __restrict__ bias, const float* __restrict__ x1b,
    const float* __restrict__ ada, float* __restrict__ outb,
    int rows_per_batch) {
  __shared__ float As[8][128];
  __shared__ float Ws[8][128];
  const int tid = threadIdx.x;
  const int bm = blockIdx.y * 128;
  const int bn = blockIdx.x * 128;
  const int arow = tid >> 1, acg = (tid & 1) * 4;
  const int wrow = tid >> 5, wcol = (tid & 31) * 4;
  const int tx = tid & 15, ty = tid >> 4;
  float acc[8][8];
  #pragma unroll
  for (int i = 0; i < 8; i++)
    #pragma unroll
    for (int j = 0; j < 8; j++) acc[i][j] = 0.f;

  for (int k0 = 0; k0 < HID; k0 += 8) {
    {
      int ak = k0 + acg;
      const float* hrow = h12b + (size_t)(bm + arow) * N12;
      float a0 = 0.f, a1 = 0.f, a2 = 0.f, a3 = 0.f;
      if (ak + 3 < HID) {
        float4 h1 = *(const float4*)(hrow + ak);
        float2 h2a = *(const float2*)(hrow + HID + ak);
        float2 h2b = *(const float2*)(hrow + HID + ak + 2);
        a0 = siluf(h1.x) * h2a.x;
        a1 = siluf(h1.y) * h2a.y;
        a2 = siluf(h1.z) * h2b.x;
        a3 = siluf(h1.w) * h2b.y;
      } else {
        if (ak + 0 < HID) a0 = siluf(hrow[ak + 0]) * hrow[HID + ak + 0];
        if (ak + 1 < HID) a1 = siluf(hrow[ak + 1]) * hrow[HID + ak + 1];
        if (ak + 2 < HID) a2 = siluf(hrow[ak + 2]) * hrow[HID + ak + 2];
      }
      As[acg + 0][arow] = a0;
      As[acg + 1][arow] = a1;
      As[acg + 2][arow] = a2;
      As[acg + 3][arow] = a3;
    }
    {
      int wk = k0 + wrow;
      float4 wv = make_float4(0.f, 0.f, 0.f, 0.f);
      if (wk < HID) wv = *(const float4*)(W + (size_t)wk * CDIM + bn + wcol);
      *(float4*)&Ws[wrow][wcol] = wv;
    }
    __syncthreads();
    #pragma unroll
    for (int k = 0; k < 8; k++) {
      float a[8], w[8];
      *(float4*)&a[0] = *(float4*)&As[k][ty * 4];
      *(float4*)&a[4] = *(float4*)&As[k][64 + ty * 4];
      *(float4*)&w[0] = *(float4*)&Ws[k][tx * 4];
      *(float4*)&w[4] = *(float4*)&Ws[k][64 + tx * 4];
      #pragma unroll
      for (int i = 0; i < 8; i++)
        #pragma unroll
        for (int j = 0; j < 8; j++) acc[i][j] += a[i] * w[j];
    }
    __syncthreads();
  }
  #pragma unroll
  for (int i = 0; i < 8; i++) {
    int row = bm + ((i < 4) ? ty * 4 + i : 64 + ty * 4 + (i - 4));
    int b = row / rows_per_batch;
    #pragma unroll
    for (int h = 0; h < 2; h++) {
      int col = bn + h * 64 + tx * 4;
      float4 gm = *(const float4*)&ada[b * N6C + 5 * CDIM + col];
      float4 bv = *(const float4*)&bias[col];
      float4 xr = *(const float4*)&x1b[(size_t)row * CDIM + col];
      float4 o;
      o.x = xr.x + gm.x * (acc[i][h * 4 + 0] + bv.x);
      o.y = xr.y + gm.y * (acc[i][h * 4 + 1] + bv.y);
      o.z = xr.z + gm.z * (acc[i][h * 4 + 2] + bv.z);
      o.w = xr.w + gm.w * (acc[i][h * 4 + 3] + bv.w);
      *(float4*)&outb[(size_t)row * CDIM + col] = o;
    }
  }
}

extern "C" void kernel_launch(void* const* d_in, const int* in_sizes, int n_in,
                              void* d_out, int out_size, void* d_ws, size_t ws_size,
                              hipStream_t stream) {
  const float* x_pixel = (const float*)d_in[0];
  const float* x_dino  = (const float*)d_in[1];
  const float* c       = (const float*)d_in[2];
  const float* w_ada_p = (const float*)d_in[3];
  const float* b_ada_p = (const float*)d_in[4];
  const float* w_ada_d = (const float*)d_in[5];
  const float* b_ada_d = (const float*)d_in[6];
  const float* g_n1p   = (const float*)d_in[7];
  const float* g_n1d   = (const float*)d_in[8];
  const float* g_n2p   = (const float*)d_in[9];
  const float* g_n2d   = (const float*)d_in[10];
  const float* w_qkv   = (const float*)d_in[11];
  const float* b_qkv   = (const float*)d_in[12];
  const float* g_qn    = (const float*)d_in[13];
  const float* g_kn    = (const float*)d_in[14];
  const float* w_proj  = (const float*)d_in[15];
  const float* b_proj  = (const float*)d_in[16];
  const float* w12_p   = (const float*)d_in[17];
  const float* b12_p   = (const float*)d_in[18];
  const float* w3_p    = (const float*)d_in[19];
  const float* b3_p    = (const float*)d_in[20];
  const float* w12_d   = (const float*)d_in[21];
  const float* b12_d   = (const float*)d_in[22];
  const float* w3_d    = (const float*)d_in[23];
  const float* b3_d    = (const float*)d_in[24];
  const int*   blk     = (const int*)d_in[25];
  float* out = (float*)d_out;
  float* ws  = (float*)d_ws;

  float* sc    = ws + OFF_SC;
  float* ada_p = ws + OFF_ADAP;
  float* ada_d = ws + OFF_ADAD;
  float* rope  = ws + OFF_ROPE;
  float* xc    = ws + OFF_XC;
  float* qkv   = ws + OFF_QKV;
  float* Qb    = ws + OFF_Q;
  float* Kb    = ws + OFF_K;
  float* Vb    = ws + OFF_V;
  float* Ob    = ws + OFF_O;
  float* x1    = ws + OFF_X1;
  float* mlpin = ws + OFF_MLPIN;
  float* h12   = ws + OFF_H12;

  hipLaunchKernelGGL(k_silu, dim3(16), dim3(256), 0, stream, c, sc, BATCH * CDIM);
  hipLaunchKernelGGL(k_ada, dim3(24, 2), dim3(256), 0, stream,
                     sc, w_ada_p, b_ada_p, w_ada_d, b_ada_d, ada_p, ada_d);
  hipLaunchKernelGGL(k_ropetab, dim3(NP), dim3(64), 0, stream, rope);
  hipLaunchKernelGGL(k_rmsmod1, dim3(BATCH * NTOT), dim3(256), 0, stream,
                     x_pixel, x_dino, ada_p, ada_d, g_n1p, g_n1d, xc);
  hipLaunchKernelGGL(k_gemm_bias, dim3(3072 / 128, 5120 / 128), dim3(256), 0, stream,
                     xc, w_qkv, b_qkv, qkv, 5120, 3072, 1024);
  hipLaunchKernelGGL(k_qkvsplit, dim3(NTOT, BATCH), dim3(256), 0, stream,
                     qkv, g_qn, g_kn, rope, Qb, Kb, Vb);
  hipLaunchKernelGGL(k_attn, dim3(NTOT / 32, BATCH * NH), dim3(256), 0, stream,
                     Qb, Kb, Vb, blk, Ob);
  hipLaunchKernelGGL(k_gemm_proj, dim3(1024 / 128, 5120 / 128), dim3(256), 0, stream,
                     Ob, w_proj, b_proj, x_pixel, x_dino, ada_p, ada_d, x1);
  hipLaunchKernelGGL(k_rmsmod2, dim3(5120), dim3(256), 0, stream,
                     x1, ada_p, ada_d, g_n2p, g_n2d, mlpin);
  hipLaunchKernelGGL(k_gemm_bias, dim3(43, 4096 / 128), dim3(256), 0, stream,
                     mlpin, w12_p, b12_p, h12, 4096, N12, 1024);
  hipLaunchKernelGGL(k_gemm_bias, dim3(43, 1024 / 128), dim3(256), 0, stream,
                     mlpin + (size_t)4096 * CDIM, w12_d, b12_d,
                     h12 + (size_t)4096 * N12, 1024, N12, 1024);
  hipLaunchKernelGGL(k_gemm_mlp2, dim3(1024 / 128, 4096 / 128), dim3(256), 0, stream,
                     h12, w3_p, b3_p, x1, ada_p, out, 1024);
  hipLaunchKernelGGL(k_gemm_mlp2, dim3(1024 / 128, 1024 / 128), dim3(256), 0, stream,
                     h12 + (size_t)4096 * N12, w3_d, b3_d, x1 + (size_t)4096 * CDIM,
                     ada_d, out + (size_t)BATCH * NP * CDIM, 256);
}

// Round 3
// 1978.299 us; speedup vs baseline: 2.5583x; 1.9453x over previous
//
#include <hip/hip_runtime.h>
#include <math.h>

// ---- problem dims ----
#define BATCH 4
#define NP 1024
#define ND 256
#define NTOT 1280
#define CDIM 1024
#define NH 16
#define DHD 64
#define HID 2730
#define N12 5460
#define N6C 6144
#define EPSF 1e-6f
// padded dims for guard-free MFMA tiling
#define N12PAD 5504   // 43*128
#define HIDPAD 2752   // 43*64

typedef _Float16 f16x8 __attribute__((ext_vector_type(8)));
typedef float f32x4 __attribute__((ext_vector_type(4)));

// ---- workspace layout (float offsets). Total 50,003,968 floats = 200 MB ----
#define OFF_SC     0            // 4096
#define OFF_ADAP   4096         // 24576
#define OFF_ADAD   28672        // 24576
#define OFF_ROPE   53248        // 65536
#define OFF_WTQKV  131072       // f16 [3072][1024]  -> 1572864 fl
#define OFF_WTPROJ 1703936      // f16 [1024][1024]  -> 524288 fl
#define OFF_WT12P  2228224      // f16 [5504][1024]  -> 2818048 fl
#define OFF_WT12D  5046272      // f16 [5504][1024]
#define OFF_WT3P   7864320      // f16 [1024][2752]  -> 1409024 fl
#define OFF_WT3D   9273344      // f16 [1024][2752]
#define OFF_A      10682368     // 2621440 fl: xc16 -> O16 -> mlpin16 (f16 [5120][1024])
#define OFF_B      13303808     // 15728640 fl: qkv fp32 [5120][3072] -> h12f16 [5120][5460]
#define OFF_C      29032448     // 15728640 fl: Q,K,V fp32 -> hgate16 [5120][2752]
#define OFF_X1     44761088     // 5242880 fl fp32

__device__ __forceinline__ float siluf(float x) { return x / (1.f + expf(-x)); }

__device__ __forceinline__ float blockReduceSum256(float v) {
  __shared__ float red[4];
  #pragma unroll
  for (int o = 32; o > 0; o >>= 1) v += __shfl_down(v, o);
  if ((threadIdx.x & 63) == 0) red[threadIdx.x >> 6] = v;
  __syncthreads();
  float r = red[0] + red[1] + red[2] + red[3];
  __syncthreads();
  return r;
}

__global__ void k_silu(const float* __restrict__ c, float* __restrict__ sc, int n) {
  int i = blockIdx.x * 256 + threadIdx.x;
  if (i < n) sc[i] = siluf(c[i]);
}

__global__ __launch_bounds__(256) void k_ada(
    const float* __restrict__ sc,
    const float* __restrict__ wp, const float* __restrict__ bp,
    const float* __restrict__ wd, const float* __restrict__ bd,
    float* __restrict__ adap, float* __restrict__ adad) {
  __shared__ float s[BATCH * CDIM];
  const float* w   = blockIdx.y ? wd : wp;
  const float* bia = blockIdx.y ? bd : bp;
  float* out       = blockIdx.y ? adad : adap;
  int tid = threadIdx.x;
  for (int i = tid; i < BATCH * CDIM; i += 256) s[i] = sc[i];
  __syncthreads();
  int n = blockIdx.x * 256 + tid;
  float a0 = 0.f, a1 = 0.f, a2 = 0.f, a3 = 0.f;
  for (int k = 0; k < CDIM; k++) {
    float wv = w[(size_t)k * N6C + n];
    a0 += s[k] * wv;
    a1 += s[CDIM + k] * wv;
    a2 += s[2 * CDIM + k] * wv;
    a3 += s[3 * CDIM + k] * wv;
  }
  float bv = bia[n];
  out[0 * N6C + n] = a0 + bv;
  out[1 * N6C + n] = a1 + bv;
  out[2 * N6C + n] = a2 + bv;
  out[3 * N6C + n] = a3 + bv;
}

__global__ void k_ropetab(float* __restrict__ tab) {
  int pos = blockIdx.x;
  int i = threadIdx.x;
  if (i < 32) {
    float f = powf(10000.f, -2.f * (float)i / 64.f);
    float ang = (float)pos * f;
    tab[pos * 64 + i]      = cosf(ang);
    tab[pos * 64 + 32 + i] = sinf(ang);
  }
}

// ---- weight transpose + fp32->fp16: Wt[n][k] = (f16)W[k][n], zero-padded ----
__global__ __launch_bounds__(256) void k_wtrans(
    const float* __restrict__ W, _Float16* __restrict__ Wt,
    int Kin, int Nin, int Kpad) {
  __shared__ float S[32][33];
  const int bn = blockIdx.x, bk = blockIdx.y;
  const int tx = threadIdx.x & 31, ty = threadIdx.x >> 5;
  #pragma unroll
  for (int i = 0; i < 4; i++) {
    int k = bk * 32 + ty + i * 8;
    int n = bn * 32 + tx;
    float v = (k < Kin && n < Nin) ? W[(size_t)k * Nin + n] : 0.f;
    S[ty + i * 8][tx] = v;
  }
  __syncthreads();
  #pragma unroll
  for (int i = 0; i < 4; i++) {
    int n  = bn * 32 + ty + i * 8;
    int kc = bk * 32 + tx;
    Wt[(size_t)n * Kpad + kc] = (_Float16)S[tx][ty + i * 8];
  }
}

// ---- rms_norm + modulate -> fp16 xc ----
__global__ __launch_bounds__(256) void k_rmsmod1(
    const float* __restrict__ xp, const float* __restrict__ xd,
    const float* __restrict__ adap, const float* __restrict__ adad,
    const float* __restrict__ g1p, const float* __restrict__ g1d,
    _Float16* __restrict__ xc) {
  int r = blockIdx.x;
  int b = r / NTOT, t = r % NTOT;
  bool pix = t < NP;
  const float* src = pix ? xp + ((size_t)b * NP + t) * CDIM
                         : xd + ((size_t)b * ND + (t - NP)) * CDIM;
  const float* ada = pix ? adap : adad;
  const float* g   = pix ? g1p : g1d;
  int tid = threadIdx.x;
  float vals[4];
  float ss = 0.f;
  #pragma unroll
  for (int i = 0; i < 4; i++) {
    float x = src[tid + i * 256];
    vals[i] = x;
    ss += x * x;
  }
  ss = blockReduceSum256(ss);
  float inv = 1.f / sqrtf(ss * (1.f / CDIM) + EPSF);
  _Float16* dst = xc + (size_t)r * CDIM;
  #pragma unroll
  for (int i = 0; i < 4; i++) {
    int cx = tid + i * 256;
    float sh = ada[b * N6C + cx];
    float sl = ada[b * N6C + CDIM + cx];
    dst[cx] = (_Float16)(vals[i] * inv * g[cx] * (1.f + sl) + sh);
  }
}

// ---- fp16 MFMA GEMM: out = A16[M,K] @ Wt16[N,K]^T + bias, templated epilogue ----
// 128x128 tile, BK=64, 4 waves 2x2, per-wave 64x64 = 4x4 frags of 16x16x32.
// EPI 0: outf fp32 = v        (qkv)
// EPI 1: outh f16  = v        (mlp1 -> h12)
// EPI 2: x1 = xin + ga*v, pixel/dino routed  (proj+resid1)
// EPI 3: outf = x1row + gm*v  (mlp2+resid2)
template<int EPI>
__global__ __launch_bounds__(256) void k_hgemm(
    const _Float16* __restrict__ A, const _Float16* __restrict__ Bt,
    const float* __restrict__ bias, float* __restrict__ outf,
    _Float16* __restrict__ outh,
    const float* __restrict__ e0, const float* __restrict__ e1,
    const float* __restrict__ e2, const float* __restrict__ e3,
    int M, int Nld, int K, int rpb) {
  __shared__ _Float16 As[128 * 72];
  __shared__ _Float16 Bs[128 * 72];
  const int tid = threadIdx.x;
  const int lane = tid & 63;
  const int wid = tid >> 6;
  const int wm = wid >> 1, wn = wid & 1;
  const int bm = blockIdx.y * 128;
  const int bn = blockIdx.x * 128;
  const int lr = lane & 15, kg = lane >> 4;

  f32x4 acc[4][4];
  #pragma unroll
  for (int i = 0; i < 4; i++)
    #pragma unroll
    for (int j = 0; j < 4; j++) acc[i][j] = (f32x4){0.f, 0.f, 0.f, 0.f};

  uint4 ra[4], rb[4];
  #pragma unroll
  for (int i = 0; i < 4; i++) {
    int chunk = tid + i * 256;
    int row = chunk >> 3, c8 = chunk & 7;
    ra[i] = *(const uint4*)(A + (size_t)(bm + row) * K + c8 * 8);
    rb[i] = *(const uint4*)(Bt + (size_t)(bn + row) * K + c8 * 8);
  }

  for (int k0 = 0;;) {
    __syncthreads();
    #pragma unroll
    for (int i = 0; i < 4; i++) {
      int chunk = tid + i * 256;
      int row = chunk >> 3, c8 = chunk & 7;
      *(uint4*)&As[row * 72 + c8 * 8] = ra[i];
      *(uint4*)&Bs[row * 72 + c8 * 8] = rb[i];
    }
    __syncthreads();
    if (k0 + 64 < K) {
      #pragma unroll
      for (int i = 0; i < 4; i++) {
        int chunk = tid + i * 256;
        int row = chunk >> 3, c8 = chunk & 7;
        ra[i] = *(const uint4*)(A + (size_t)(bm + row) * K + k0 + 64 + c8 * 8);
        rb[i] = *(const uint4*)(Bt + (size_t)(bn + row) * K + k0 + 64 + c8 * 8);
      }
    }
    #pragma unroll
    for (int kk = 0; kk < 2; kk++) {
      f16x8 af[4], bf[4];
      #pragma unroll
      for (int mi = 0; mi < 4; mi++)
        af[mi] = *(const f16x8*)&As[(wm * 64 + mi * 16 + lr) * 72 + kk * 32 + kg * 8];
      #pragma unroll
      for (int nj = 0; nj < 4; nj++)
        bf[nj] = *(const f16x8*)&Bs[(wn * 64 + nj * 16 + lr) * 72 + kk * 32 + kg * 8];
      #pragma unroll
      for (int mi = 0; mi < 4; mi++)
        #pragma unroll
        for (int nj = 0; nj < 4; nj++)
          acc[mi][nj] = __builtin_amdgcn_mfma_f32_16x16x32_f16(af[mi], bf[nj], acc[mi][nj], 0, 0, 0);
    }
    k0 += 64;
    if (k0 >= K) break;
  }

  // epilogue: C row = bm + wm*64 + mi*16 + (lane>>4)*4 + r ; col = bn + wn*64 + nj*16 + (lane&15)
  #pragma unroll
  for (int mi = 0; mi < 4; mi++) {
    #pragma unroll
    for (int nj = 0; nj < 4; nj++) {
      #pragma unroll
      for (int r = 0; r < 4; r++) {
        int row = bm + wm * 64 + mi * 16 + kg * 4 + r;
        int col = bn + wn * 64 + nj * 16 + lr;
        if (col < Nld) {
          float v = acc[mi][nj][r] + bias[col];
          if constexpr (EPI == 0) {
            outf[(size_t)row * Nld + col] = v;
          } else if constexpr (EPI == 1) {
            outh[(size_t)row * Nld + col] = (_Float16)v;
          } else if constexpr (EPI == 2) {
            int b = row / NTOT, t = row % NTOT;
            if (t < NP) {
              float ga  = e2[b * N6C + 2 * CDIM + col];
              float xin = e0[((size_t)b * NP + t) * CDIM + col];
              outf[((size_t)(b * NP + t)) * CDIM + col] = xin + ga * v;
            } else {
              int td = t - NP;
              float ga  = e3[b * N6C + 2 * CDIM + col];
              float xin = e1[((size_t)b * ND + td) * CDIM + col];
              outf[((size_t)(4096 + b * ND + td)) * CDIM + col] = xin + ga * v;
            }
          } else {
            int b = row / rpb;
            float gm = e2[b * N6C + 5 * CDIM + col];
            outf[(size_t)row * CDIM + col] = e0[(size_t)row * CDIM + col] + gm * v;
          }
        }
      }
    }
  }
}

__global__ __launch_bounds__(256) void k_qkvsplit(
    const float* __restrict__ qkv, const float* __restrict__ gq,
    const float* __restrict__ gk, const float* __restrict__ tab,
    float* __restrict__ Q, float* __restrict__ K, float* __restrict__ V) {
  const int t = blockIdx.x, b = blockIdx.y;
  const int lane = threadIdx.x & 63;
  const int wv = threadIdx.x >> 6;
  const float* row = qkv + ((size_t)b * NTOT + t) * 3072;
  const int pos = (t < NP) ? t : (t - NP);
  const int fi = lane & 31;
  const float cs = tab[pos * 64 + fi];
  const float sn = tab[pos * 64 + 32 + fi];
  #pragma unroll
  for (int hg = 0; hg < 4; hg++) {
    const int h = hg * 4 + wv;
    const size_t oidx = (((size_t)b * NH + h) * NTOT + t) * DHD + lane;
    {
      float x = row[h * 64 + lane];
      float ss = x * x;
      #pragma unroll
      for (int o = 32; o > 0; o >>= 1) ss += __shfl_xor(ss, o);
      float xn = x * (1.f / sqrtf(ss * (1.f / 64.f) + EPSF)) * gq[lane];
      float p = __shfl_xor(xn, 32);
      Q[oidx] = (lane < 32) ? (xn * cs - p * sn) : (p * sn + xn * cs);
    }
    {
      float x = row[1024 + h * 64 + lane];
      float ss = x * x;
      #pragma unroll
      for (int o = 32; o > 0; o >>= 1) ss += __shfl_xor(ss, o);
      float xn = x * (1.f / sqrtf(ss * (1.f / 64.f) + EPSF)) * gk[lane];
      float p = __shfl_xor(xn, 32);
      K[oidx] = (lane < 32) ? (xn * cs - p * sn) : (p * sn + xn * cs);
    }
    V[oidx] = row[2048 + h * 64 + lane];
  }
}

// ---- flash attention fp32 (bank-conflict-free), fp16 output ----
#define LROW 68
__global__ __launch_bounds__(256) void k_attn(
    const float* __restrict__ Q, const float* __restrict__ Kg,
    const float* __restrict__ V, const int* __restrict__ blk,
    _Float16* __restrict__ O) {
  __shared__ float qs[32][LROW];
  __shared__ float ks[32][LROW];
  __shared__ float vs[32][LROW];
  const int bh = blockIdx.y;
  const int b = bh >> 4, h = bh & 15;
  const int q0 = blockIdx.x * 32;
  const float* Qb = Q + (size_t)bh * NTOT * DHD;
  const float* Kb = Kg + (size_t)bh * NTOT * DHD;
  const float* Vb = V + (size_t)bh * NTOT * DHD;
  const int tid = threadIdx.x;
  {
    const float4* src = (const float4*)(Qb + (size_t)q0 * DHD);
    #pragma unroll
    for (int i = 0; i < 2; i++) {
      int e = tid + i * 256;
      int row = e >> 4, c4 = e & 15;
      ((float4*)qs)[row * (LROW / 4) + c4] = src[e];
    }
  }
  const int r = tid >> 3, g = tid & 7;
  const int d0 = g * 8;
  float acc[8] = {0.f, 0.f, 0.f, 0.f, 0.f, 0.f, 0.f, 0.f};
  float mrow = -INFINITY, lrow = 0.f;
  const bool blocked_b = blk[b] != 0;
  const bool qpix = (q0 + r) < NP;
  const int gbase = (tid & 63) & ~7;

  for (int kb = 0; kb < NTOT; kb += 32) {
    __syncthreads();
    {
      const float4* ksrc = (const float4*)(Kb + (size_t)kb * DHD);
      const float4* vsrc = (const float4*)(Vb + (size_t)kb * DHD);
      #pragma unroll
      for (int i = 0; i < 2; i++) {
        int e = tid + i * 256;
        int row = e >> 4, c4 = e & 15;
        ((float4*)ks)[row * (LROW / 4) + c4] = ksrc[e];
        ((float4*)vs)[row * (LROW / 4) + c4] = vsrc[e];
      }
    }
    __syncthreads();
    float s[4];
    #pragma unroll
    for (int jj = 0; jj < 4; jj++) {
      int j = jj * 8 + g;
      float dot = 0.f;
      #pragma unroll
      for (int d = 0; d < 64; d += 4) {
        float4 qv = *(float4*)&qs[r][d];
        float4 kv = *(float4*)&ks[j][d];
        dot += qv.x * kv.x + qv.y * kv.y + qv.z * kv.z + qv.w * kv.w;
      }
      s[jj] = dot * 0.125f;
      if (blocked_b && qpix && (kb + j >= NP)) s[jj] = -INFINITY;
    }
    float pm = fmaxf(fmaxf(s[0], s[1]), fmaxf(s[2], s[3]));
    pm = fmaxf(pm, __shfl_xor(pm, 1));
    pm = fmaxf(pm, __shfl_xor(pm, 2));
    pm = fmaxf(pm, __shfl_xor(pm, 4));
    float mn = fmaxf(mrow, pm);
    float corr = expf(mrow - mn);
    float p[4];
    float ls = 0.f;
    #pragma unroll
    for (int jj = 0; jj < 4; jj++) { p[jj] = expf(s[jj] - mn); ls += p[jj]; }
    ls += __shfl_xor(ls, 1);
    ls += __shfl_xor(ls, 2);
    ls += __shfl_xor(ls, 4);
    lrow = lrow * corr + ls;
    mrow = mn;
    #pragma unroll
    for (int d = 0; d < 8; d++) acc[d] *= corr;
    #pragma unroll
    for (int jj = 0; jj < 4; jj++) {
      #pragma unroll
      for (int gp = 0; gp < 8; gp++) {
        float pj = __shfl(p[jj], gbase + gp);
        int j = jj * 8 + gp;
        float4 v0 = *(float4*)&vs[j][d0];
        float4 v1 = *(float4*)&vs[j][d0 + 4];
        acc[0] += pj * v0.x; acc[1] += pj * v0.y;
        acc[2] += pj * v0.z; acc[3] += pj * v0.w;
        acc[4] += pj * v1.x; acc[5] += pj * v1.y;
        acc[6] += pj * v1.z; acc[7] += pj * v1.w;
      }
    }
  }
  float invl = 1.f / lrow;
  _Float16* orow = O + ((size_t)(b * NTOT + q0 + r)) * CDIM + h * 64 + d0;
  f16x8 o;
  #pragma unroll
  for (int d = 0; d < 8; d++) o[d] = (_Float16)(acc[d] * invl);
  *(f16x8*)orow = o;
}

// ---- second norm+modulate on x1 -> fp16 mlpin ----
__global__ __launch_bounds__(256) void k_rmsmod2(
    const float* __restrict__ x1,
    const float* __restrict__ adap, const float* __restrict__ adad,
    const float* __restrict__ g2p, const float* __restrict__ g2d,
    _Float16* __restrict__ mlpin) {
  int r = blockIdx.x;
  bool pix = r < 4096;
  int b = pix ? (r >> 10) : ((r - 4096) >> 8);
  const float* ada = pix ? adap : adad;
  const float* g   = pix ? g2p : g2d;
  const float* src = x1 + (size_t)r * CDIM;
  int tid = threadIdx.x;
  float vals[4];
  float ss = 0.f;
  #pragma unroll
  for (int i = 0; i < 4; i++) {
    float x = src[tid + i * 256];
    vals[i] = x;
    ss += x * x;
  }
  ss = blockReduceSum256(ss);
  float inv = 1.f / sqrtf(ss * (1.f / CDIM) + EPSF);
  _Float16* dst = mlpin + (size_t)r * CDIM;
  #pragma unroll
  for (int i = 0; i < 4; i++) {
    int cx = tid + i * 256;
    float sh = ada[b * N6C + 3 * CDIM + cx];
    float sl = ada[b * N6C + 4 * CDIM + cx];
    dst[cx] = (_Float16)(vals[i] * inv * g[cx] * (1.f + sl) + sh);
  }
}

// ---- swiglu gate: hgate[m][k] = silu(h1)*h2, fp16, zero-padded to HIDPAD ----
__global__ void k_swiglu(const _Float16* __restrict__ h12, _Float16* __restrict__ hg) {
  int r = blockIdx.x;
  const _Float16* h1 = h12 + (size_t)r * N12;
  const _Float16* h2 = h1 + HID;
  _Float16* o = hg + (size_t)r * HIDPAD;
  for (int j = threadIdx.x; j < HIDPAD; j += 256) {
    float v = 0.f;
    if (j < HID) {
      float a = (float)h1[j];
      v = (a / (1.f + expf(-a))) * (float)h2[j];
    }
    o[j] = (_Float16)v;
  }
}

extern "C" void kernel_launch(void* const* d_in, const int* in_sizes, int n_in,
                              void* d_out, int out_size, void* d_ws, size_t ws_size,
                              hipStream_t stream) {
  const float* x_pixel = (const float*)d_in[0];
  const float* x_dino  = (const float*)d_in[1];
  const float* c       = (const float*)d_in[2];
  const float* w_ada_p = (const float*)d_in[3];
  const float* b_ada_p = (const float*)d_in[4];
  const float* w_ada_d = (const float*)d_in[5];
  const float* b_ada_d = (const float*)d_in[6];
  const float* g_n1p   = (const float*)d_in[7];
  const float* g_n1d   = (const float*)d_in[8];
  const float* g_n2p   = (const float*)d_in[9];
  const float* g_n2d   = (const float*)d_in[10];
  const float* w_qkv   = (const float*)d_in[11];
  const float* b_qkv   = (const float*)d_in[12];
  const float* g_qn    = (const float*)d_in[13];
  const float* g_kn    = (const float*)d_in[14];
  const float* w_proj  = (const float*)d_in[15];
  const float* b_proj  = (const float*)d_in[16];
  const float* w12_p   = (const float*)d_in[17];
  const float* b12_p   = (const float*)d_in[18];
  const float* w3_p    = (const float*)d_in[19];
  const float* b3_p    = (const float*)d_in[20];
  const float* w12_d   = (const float*)d_in[21];
  const float* b12_d   = (const float*)d_in[22];
  const float* w3_d    = (const float*)d_in[23];
  const float* b3_d    = (const float*)d_in[24];
  const int*   blk     = (const int*)d_in[25];
  float* out = (float*)d_out;
  float* ws  = (float*)d_ws;

  float* sc     = ws + OFF_SC;
  float* ada_p  = ws + OFF_ADAP;
  float* ada_d  = ws + OFF_ADAD;
  float* rope   = ws + OFF_ROPE;
  _Float16* wtqkv  = (_Float16*)(ws + OFF_WTQKV);
  _Float16* wtproj = (_Float16*)(ws + OFF_WTPROJ);
  _Float16* wt12p  = (_Float16*)(ws + OFF_WT12P);
  _Float16* wt12d  = (_Float16*)(ws + OFF_WT12D);
  _Float16* wt3p   = (_Float16*)(ws + OFF_WT3P);
  _Float16* wt3d   = (_Float16*)(ws + OFF_WT3D);
  _Float16* actA   = (_Float16*)(ws + OFF_A);   // xc16 -> O16 -> mlpin16
  float*    qkv    = ws + OFF_B;                // fp32 [5120][3072]
  _Float16* h12f   = (_Float16*)(ws + OFF_B);   // later: f16 [5120][5460]
  float*    Qb     = ws + OFF_C;
  float*    Kb     = ws + OFF_C + 5242880;
  float*    Vb     = ws + OFF_C + 10485760;
  _Float16* hgate  = (_Float16*)(ws + OFF_C);   // later: f16 [5120][2752]
  float*    x1     = ws + OFF_X1;

  hipLaunchKernelGGL(k_silu, dim3(16), dim3(256), 0, stream, c, sc, BATCH * CDIM);
  hipLaunchKernelGGL(k_ada, dim3(24, 2), dim3(256), 0, stream,
                     sc, w_ada_p, b_ada_p, w_ada_d, b_ada_d, ada_p, ada_d);
  hipLaunchKernelGGL(k_ropetab, dim3(NP), dim3(64), 0, stream, rope);
  // weight transposes (fp32 -> fp16 [N][K], zero-padded)
  hipLaunchKernelGGL(k_wtrans, dim3(3072 / 32, 1024 / 32), dim3(256), 0, stream,
                     w_qkv, wtqkv, 1024, 3072, 1024);
  hipLaunchKernelGGL(k_wtrans, dim3(1024 / 32, 1024 / 32), dim3(256), 0, stream,
                     w_proj, wtproj, 1024, 1024, 1024);
  hipLaunchKernelGGL(k_wtrans, dim3(N12PAD / 32, 1024 / 32), dim3(256), 0, stream,
                     w12_p, wt12p, 1024, N12, 1024);
  hipLaunchKernelGGL(k_wtrans, dim3(N12PAD / 32, 1024 / 32), dim3(256), 0, stream,
                     w12_d, wt12d, 1024, N12, 1024);
  hipLaunchKernelGGL(k_wtrans, dim3(1024 / 32, HIDPAD / 32), dim3(256), 0, stream,
                     w3_p, wt3p, HID, 1024, HIDPAD);
  hipLaunchKernelGGL(k_wtrans, dim3(1024 / 32, HIDPAD / 32), dim3(256), 0, stream,
                     w3_d, wt3d, HID, 1024, HIDPAD);

  hipLaunchKernelGGL(k_rmsmod1, dim3(BATCH * NTOT), dim3(256), 0, stream,
                     x_pixel, x_dino, ada_p, ada_d, g_n1p, g_n1d, actA);
  hipLaunchKernelGGL(k_hgemm<0>, dim3(3072 / 128, 5120 / 128), dim3(256), 0, stream,
                     actA, wtqkv, b_qkv, qkv, (_Float16*)nullptr,
                     nullptr, nullptr, nullptr, nullptr, 5120, 3072, 1024, 0);
  hipLaunchKernelGGL(k_qkvsplit, dim3(NTOT, BATCH), dim3(256), 0, stream,
                     qkv, g_qn, g_kn, rope, Qb, Kb, Vb);
  hipLaunchKernelGGL(k_attn, dim3(NTOT / 32, BATCH * NH), dim3(256), 0, stream,
                     Qb, Kb, Vb, blk, actA);   // actA now O16
  hipLaunchKernelGGL(k_hgemm<2>, dim3(1024 / 128, 5120 / 128), dim3(256), 0, stream,
                     actA, wtproj, b_proj, x1, (_Float16*)nullptr,
                     x_pixel, x_dino, ada_p, ada_d, 5120, 1024, 1024, 0);
  hipLaunchKernelGGL(k_rmsmod2, dim3(5120), dim3(256), 0, stream,
                     x1, ada_p, ada_d, g_n2p, g_n2d, actA);  // actA now mlpin16
  hipLaunchKernelGGL(k_hgemm<1>, dim3(N12PAD / 128, 4096 / 128), dim3(256), 0, stream,
                     actA, wt12p, b12_p, nullptr, h12f,
                     nullptr, nullptr, nullptr, nullptr, 4096, N12, 1024, 0);
  hipLaunchKernelGGL(k_hgemm<1>, dim3(N12PAD / 128, 1024 / 128), dim3(256), 0, stream,
                     actA + (size_t)4096 * CDIM, wt12d, b12_d, nullptr,
                     h12f + (size_t)4096 * N12,
                     nullptr, nullptr, nullptr, nullptr, 1024, N12, 1024, 0);
  hipLaunchKernelGGL(k_swiglu, dim3(5120), dim3(256), 0, stream, h12f, hgate);
  hipLaunchKernelGGL(k_hgemm<3>, dim3(1024 / 128, 4096 / 128), dim3(256), 0, stream,
                     hgate, wt3p, b3_p, out, (_Float16*)nullptr,
                     x1, nullptr, ada_p, nullptr, 4096, 1024, HIDPAD, 1024);
  hipLaunchKernelGGL(k_hgemm<3>, dim3(1024 / 128, 1024 / 128), dim3(256), 0, stream,
                     hgate + (size_t)4096 * HIDPAD, wt3d, b3_d, out + (size_t)4096 * CDIM,
                     (_Float16*)nullptr,
                     x1 + (size_t)4096 * CDIM, nullptr, ada_d, nullptr, 1024, 1024, HIDPAD, 256);
}

// Round 5
// 1353.963 us; speedup vs baseline: 3.7379x; 1.4611x over previous
//
#include <hip/hip_runtime.h>
#include <math.h>

// ---- problem dims ----
#define BATCH 4
#define NP 1024
#define ND 256
#define NTOT 1280
#define CDIM 1024
#define NH 16
#define DHD 64
#define HID 2730
#define N12 5460
#define N6C 6144
#define EPSF 1e-6f
// padded dims for guard-free MFMA tiling
#define N12PAD 5504   // 43*128
#define HIDPAD 2752   // 43*64

typedef _Float16 f16x8 __attribute__((ext_vector_type(8)));
typedef float f32x4 __attribute__((ext_vector_type(4)));

// ---- workspace layout (float offsets) ----
#define OFF_SC     0            // 4096
#define OFF_ADAP   4096         // 24576
#define OFF_ADAD   28672        // 24576
#define OFF_ROPE   53248        // 65536
#define OFF_WTQKV  131072       // f16 [3072][1024]
#define OFF_WTPROJ 1703936      // f16 [1024][1024]
#define OFF_WT12P  2228224      // f16 [5504][1024]
#define OFF_WT12D  5046272
#define OFF_WT3P   7864320      // f16 [1024][2752]
#define OFF_WT3D   9273344
#define OFF_A      10682368     // f16 [5120][1024]: xc16 -> O16 -> mlpin16
#define OFF_B      13303808     // qkv fp32 [5120][3072] -> h12 f16 [5120][5460]
#define OFF_C      29032448     // Qh,Kh,Vh f16 [64][1280][64] -> hgate f16 [5120][2752]
#define OFF_X1     44761088     // fp32 [5120][1024]

// LDS swizzles (bank-conflict-free patterns, see round-4 analysis)
#define SWZB(row, inner) ((inner) ^ (((row) & 7) << 4) ^ (((row) & 24) << 2))
#define SWZP(row, inner) ((inner) ^ (((row) & 7) << 4) ^ ((((row) >> 2) & 3) << 5))

__device__ __forceinline__ float siluf(float x) { return x / (1.f + expf(-x)); }

__device__ __forceinline__ float blockReduceSum256(float v) {
  __shared__ float red[4];
  #pragma unroll
  for (int o = 32; o > 0; o >>= 1) v += __shfl_down(v, o);
  if ((threadIdx.x & 63) == 0) red[threadIdx.x >> 6] = v;
  __syncthreads();
  float r = red[0] + red[1] + red[2] + red[3];
  __syncthreads();
  return r;
}

__global__ void k_silu(const float* __restrict__ c, float* __restrict__ sc, int n) {
  int i = blockIdx.x * 256 + threadIdx.x;
  if (i < n) sc[i] = siluf(c[i]);
}

__global__ __launch_bounds__(256) void k_ada(
    const float* __restrict__ sc,
    const float* __restrict__ wp, const float* __restrict__ bp,
    const float* __restrict__ wd, const float* __restrict__ bd,
    float* __restrict__ adap, float* __restrict__ adad) {
  __shared__ float s[BATCH * CDIM];
  const float* w   = blockIdx.y ? wd : wp;
  const float* bia = blockIdx.y ? bd : bp;
  float* out       = blockIdx.y ? adad : adap;
  int tid = threadIdx.x;
  for (int i = tid; i < BATCH * CDIM; i += 256) s[i] = sc[i];
  __syncthreads();
  int n = blockIdx.x * 256 + tid;
  float a0 = 0.f, a1 = 0.f, a2 = 0.f, a3 = 0.f;
  for (int k = 0; k < CDIM; k++) {
    float wv = w[(size_t)k * N6C + n];
    a0 += s[k] * wv;
    a1 += s[CDIM + k] * wv;
    a2 += s[2 * CDIM + k] * wv;
    a3 += s[3 * CDIM + k] * wv;
  }
  float bv = bia[n];
  out[0 * N6C + n] = a0 + bv;
  out[1 * N6C + n] = a1 + bv;
  out[2 * N6C + n] = a2 + bv;
  out[3 * N6C + n] = a3 + bv;
}

__global__ void k_ropetab(float* __restrict__ tab) {
  int pos = blockIdx.x;
  int i = threadIdx.x;
  if (i < 32) {
    float f = powf(10000.f, -2.f * (float)i / 64.f);
    float ang = (float)pos * f;
    tab[pos * 64 + i]      = cosf(ang);
    tab[pos * 64 + 32 + i] = sinf(ang);
  }
}

// ---- weight transpose + fp32->fp16 ----
__global__ __launch_bounds__(256) void k_wtrans(
    const float* __restrict__ W, _Float16* __restrict__ Wt,
    int Kin, int Nin, int Kpad) {
  __shared__ float S[32][33];
  const int bn = blockIdx.x, bk = blockIdx.y;
  const int tx = threadIdx.x & 31, ty = threadIdx.x >> 5;
  #pragma unroll
  for (int i = 0; i < 4; i++) {
    int k = bk * 32 + ty + i * 8;
    int n = bn * 32 + tx;
    float v = (k < Kin && n < Nin) ? W[(size_t)k * Nin + n] : 0.f;
    S[ty + i * 8][tx] = v;
  }
  __syncthreads();
  #pragma unroll
  for (int i = 0; i < 4; i++) {
    int n  = bn * 32 + ty + i * 8;
    int kc = bk * 32 + tx;
    Wt[(size_t)n * Kpad + kc] = (_Float16)S[tx][ty + i * 8];
  }
}

// ---- rms_norm + modulate -> fp16 xc ----
__global__ __launch_bounds__(256) void k_rmsmod1(
    const float* __restrict__ xp, const float* __restrict__ xd,
    const float* __restrict__ adap, const float* __restrict__ adad,
    const float* __restrict__ g1p, const float* __restrict__ g1d,
    _Float16* __restrict__ xc) {
  int r = blockIdx.x;
  int b = r / NTOT, t = r % NTOT;
  bool pix = t < NP;
  const float* src = pix ? xp + ((size_t)b * NP + t) * CDIM
                         : xd + ((size_t)b * ND + (t - NP)) * CDIM;
  const float* ada = pix ? adap : adad;
  const float* g   = pix ? g1p : g1d;
  int tid = threadIdx.x;
  float vals[4];
  float ss = 0.f;
  #pragma unroll
  for (int i = 0; i < 4; i++) {
    float x = src[tid + i * 256];
    vals[i] = x;
    ss += x * x;
  }
  ss = blockReduceSum256(ss);
  float inv = 1.f / sqrtf(ss * (1.f / CDIM) + EPSF);
  _Float16* dst = xc + (size_t)r * CDIM;
  #pragma unroll
  for (int i = 0; i < 4; i++) {
    int cx = tid + i * 256;
    float sh = ada[b * N6C + cx];
    float sl = ada[b * N6C + CDIM + cx];
    dst[cx] = (_Float16)(vals[i] * inv * g[cx] * (1.f + sl) + sh);
  }
}

// ---- fp16 MFMA GEMM ----
template<int EPI>
__global__ __launch_bounds__(256) void k_hgemm(
    const _Float16* __restrict__ A, const _Float16* __restrict__ Bt,
    const float* __restrict__ bias, float* __restrict__ outf,
    _Float16* __restrict__ outh,
    const float* __restrict__ e0, const float* __restrict__ e1,
    const float* __restrict__ e2, const float* __restrict__ e3,
    int M, int Nld, int K, int rpb) {
  __shared__ _Float16 As[128 * 72];
  __shared__ _Float16 Bs[128 * 72];
  const int tid = threadIdx.x;
  const int lane = tid & 63;
  const int wid = tid >> 6;
  const int wm = wid >> 1, wn = wid & 1;
  const int bm = blockIdx.y * 128;
  const int bn = blockIdx.x * 128;
  const int lr = lane & 15, kg = lane >> 4;

  f32x4 acc[4][4];
  #pragma unroll
  for (int i = 0; i < 4; i++)
    #pragma unroll
    for (int j = 0; j < 4; j++) acc[i][j] = (f32x4){0.f, 0.f, 0.f, 0.f};

  uint4 ra[4], rb[4];
  #pragma unroll
  for (int i = 0; i < 4; i++) {
    int chunk = tid + i * 256;
    int row = chunk >> 3, c8 = chunk & 7;
    ra[i] = *(const uint4*)(A + (size_t)(bm + row) * K + c8 * 8);
    rb[i] = *(const uint4*)(Bt + (size_t)(bn + row) * K + c8 * 8);
  }

  for (int k0 = 0;;) {
    __syncthreads();
    #pragma unroll
    for (int i = 0; i < 4; i++) {
      int chunk = tid + i * 256;
      int row = chunk >> 3, c8 = chunk & 7;
      *(uint4*)&As[row * 72 + c8 * 8] = ra[i];
      *(uint4*)&Bs[row * 72 + c8 * 8] = rb[i];
    }
    __syncthreads();
    if (k0 + 64 < K) {
      #pragma unroll
      for (int i = 0; i < 4; i++) {
        int chunk = tid + i * 256;
        int row = chunk >> 3, c8 = chunk & 7;
        ra[i] = *(const uint4*)(A + (size_t)(bm + row) * K + k0 + 64 + c8 * 8);
        rb[i] = *(const uint4*)(Bt + (size_t)(bn + row) * K + k0 + 64 + c8 * 8);
      }
    }
    #pragma unroll
    for (int kk = 0; kk < 2; kk++) {
      f16x8 af[4], bf[4];
      #pragma unroll
      for (int mi = 0; mi < 4; mi++)
        af[mi] = *(const f16x8*)&As[(wm * 64 + mi * 16 + lr) * 72 + kk * 32 + kg * 8];
      #pragma unroll
      for (int nj = 0; nj < 4; nj++)
        bf[nj] = *(const f16x8*)&Bs[(wn * 64 + nj * 16 + lr) * 72 + kk * 32 + kg * 8];
      #pragma unroll
      for (int mi = 0; mi < 4; mi++)
        #pragma unroll
        for (int nj = 0; nj < 4; nj++)
          acc[mi][nj] = __builtin_amdgcn_mfma_f32_16x16x32_f16(af[mi], bf[nj], acc[mi][nj], 0, 0, 0);
    }
    k0 += 64;
    if (k0 >= K) break;
  }

  #pragma unroll
  for (int mi = 0; mi < 4; mi++) {
    #pragma unroll
    for (int nj = 0; nj < 4; nj++) {
      #pragma unroll
      for (int r = 0; r < 4; r++) {
        int row = bm + wm * 64 + mi * 16 + kg * 4 + r;
        int col = bn + wn * 64 + nj * 16 + lr;
        if (col < Nld) {
          float v = acc[mi][nj][r] + bias[col];
          if constexpr (EPI == 0) {
            outf[(size_t)row * Nld + col] = v;
          } else if constexpr (EPI == 1) {
            outh[(size_t)row * Nld + col] = (_Float16)v;
          } else if constexpr (EPI == 2) {
            int b = row / NTOT, t = row % NTOT;
            if (t < NP) {
              float ga  = e2[b * N6C + 2 * CDIM + col];
              float xin = e0[((size_t)b * NP + t) * CDIM + col];
              outf[((size_t)(b * NP + t)) * CDIM + col] = xin + ga * v;
            } else {
              int td = t - NP;
              float ga  = e3[b * N6C + 2 * CDIM + col];
              float xin = e1[((size_t)b * ND + td) * CDIM + col];
              outf[((size_t)(4096 + b * ND + td)) * CDIM + col] = xin + ga * v;
            }
          } else {
            int b = row / rpb;
            float gm = e2[b * N6C + 5 * CDIM + col];
            outf[(size_t)row * CDIM + col] = e0[(size_t)row * CDIM + col] + gm * v;
          }
        }
      }
    }
  }
}

// ---- qkv split -> f16 Q (prescaled 1/8), K, V in (B*H, NTOT, 64) ----
__global__ __launch_bounds__(256) void k_qkvsplit(
    const float* __restrict__ qkv, const float* __restrict__ gq,
    const float* __restrict__ gk, const float* __restrict__ tab,
    _Float16* __restrict__ Q, _Float16* __restrict__ K, _Float16* __restrict__ V) {
  const int t = blockIdx.x, b = blockIdx.y;
  const int lane = threadIdx.x & 63;
  const int wv = threadIdx.x >> 6;
  const float* row = qkv + ((size_t)b * NTOT + t) * 3072;
  const int pos = (t < NP) ? t : (t - NP);
  const int fi = lane & 31;
  const float cs = tab[pos * 64 + fi];
  const float sn = tab[pos * 64 + 32 + fi];
  #pragma unroll
  for (int hg = 0; hg < 4; hg++) {
    const int h = hg * 4 + wv;
    const size_t oidx = (((size_t)b * NH + h) * NTOT + t) * DHD + lane;
    {
      float x = row[h * 64 + lane];
      float ss = x * x;
      #pragma unroll
      for (int o = 32; o > 0; o >>= 1) ss += __shfl_xor(ss, o);
      float xn = x * (1.f / sqrtf(ss * (1.f / 64.f) + EPSF)) * gq[lane];
      float p = __shfl_xor(xn, 32);
      float rq = (lane < 32) ? (xn * cs - p * sn) : (p * sn + xn * cs);
      Q[oidx] = (_Float16)(rq * 0.125f);
    }
    {
      float x = row[1024 + h * 64 + lane];
      float ss = x * x;
      #pragma unroll
      for (int o = 32; o > 0; o >>= 1) ss += __shfl_xor(ss, o);
      float xn = x * (1.f / sqrtf(ss * (1.f / 64.f) + EPSF)) * gk[lane];
      float p = __shfl_xor(xn, 32);
      K[oidx] = (_Float16)((lane < 32) ? (xn * cs - p * sn) : (p * sn + xn * cs));
    }
    V[oidx] = (_Float16)row[2048 + h * 64 + lane];
  }
}

// ---- MFMA flash attention: QBLK=64 (4 waves x 16 q), KVBLK=64, f16 in, f16 out ----
__global__ __launch_bounds__(256) void k_attn(
    const _Float16* __restrict__ Qh, const _Float16* __restrict__ Kh,
    const _Float16* __restrict__ Vh, const int* __restrict__ blk,
    _Float16* __restrict__ O) {
  __shared__ _Float16 Ks[64 * 64];
  __shared__ _Float16 Vs[64 * 64];
  __shared__ _Float16 Ps[4][16 * 64];
  const int bh = blockIdx.y;
  const int b = bh >> 4, h = bh & 15;
  const int q0 = blockIdx.x * 64;
  const int tid = threadIdx.x;
  const int lane = tid & 63;
  const int wid = tid >> 6;
  const int lr = lane & 15, kg = lane >> 4;

  const _Float16* Qb = Qh + (size_t)bh * NTOT * DHD;
  const _Float16* Kb = Kh + (size_t)bh * NTOT * DHD;
  const _Float16* Vb = Vh + (size_t)bh * NTOT * DHD;
  char* KsB = (char*)Ks;
  char* VsB = (char*)Vs;
  char* PsB = (char*)Ps[wid];

  // Q fragments in registers (A operand: row=q_local=lr, k=kg*8+j [+32*ks])
  f16x8 qA[2];
  {
    const _Float16* qrow = Qb + (size_t)(q0 + wid * 16 + lr) * DHD;
    qA[0] = *(const f16x8*)(qrow + kg * 8);
    qA[1] = *(const f16x8*)(qrow + 32 + kg * 8);
  }

  const int kvend = (blk[b] != 0 && q0 < NP) ? NP : NTOT;

  f32x4 acc_o[4];
  #pragma unroll
  for (int d = 0; d < 4; d++) acc_o[d] = (f32x4){0.f, 0.f, 0.f, 0.f};
  float m[4] = {-INFINITY, -INFINITY, -INFINITY, -INFINITY};
  float l[4] = {0.f, 0.f, 0.f, 0.f};

  // prefetch tile 0
  uint4 kreg[2], vreg[2];
  #pragma unroll
  for (int i = 0; i < 2; i++) {
    int chunk = tid + i * 256;
    int row = chunk >> 3, c = chunk & 7;
    kreg[i] = *(const uint4*)(Kb + (size_t)row * 64 + c * 8);
    vreg[i] = *(const uint4*)(Vb + (size_t)row * 64 + c * 8);
  }

  for (int kv0 = 0; kv0 < kvend; kv0 += 64) {
    __syncthreads();
    #pragma unroll
    for (int i = 0; i < 2; i++) {
      int chunk = tid + i * 256;
      int row = chunk >> 3, c = chunk & 7;
      *(uint4*)(KsB + row * 128 + SWZB(row, c * 16)) = kreg[i];
      *(uint4*)(VsB + row * 128 + SWZB(row, c * 16)) = vreg[i];
    }
    __syncthreads();
    if (kv0 + 64 < kvend) {
      #pragma unroll
      for (int i = 0; i < 2; i++) {
        int chunk = tid + i * 256;
        int row = chunk >> 3, c = chunk & 7;
        kreg[i] = *(const uint4*)(Kb + (size_t)(kv0 + 64 + row) * 64 + c * 8);
        vreg[i] = *(const uint4*)(Vb + (size_t)(kv0 + 64 + row) * 64 + c * 8);
      }
    }

    // QK^T: S[q=kg*4+r][key=kb*16+lr]
    f32x4 acc_s[4];
    #pragma unroll
    for (int kb = 0; kb < 4; kb++) acc_s[kb] = (f32x4){0.f, 0.f, 0.f, 0.f};
    #pragma unroll
    for (int ks = 0; ks < 2; ks++) {
      #pragma unroll
      for (int kb = 0; kb < 4; kb++) {
        int key = kb * 16 + lr;
        f16x8 kB = *(const f16x8*)(KsB + key * 128 + SWZB(key, kg * 16 + ks * 64));
        acc_s[kb] = __builtin_amdgcn_mfma_f32_16x16x32_f16(qA[ks], kB, acc_s[kb], 0, 0, 0);
      }
    }

    // online softmax (per lane: 4 q-rows (r) x 4 key-blocks (kb))
    float p[4][4];
    float corr[4];
    #pragma unroll
    for (int r = 0; r < 4; r++) {
      float mr = fmaxf(fmaxf(acc_s[0][r], acc_s[1][r]), fmaxf(acc_s[2][r], acc_s[3][r]));
      mr = fmaxf(mr, __shfl_xor(mr, 1));
      mr = fmaxf(mr, __shfl_xor(mr, 2));
      mr = fmaxf(mr, __shfl_xor(mr, 4));
      mr = fmaxf(mr, __shfl_xor(mr, 8));
      float mn = fmaxf(m[r], mr);
      corr[r] = __expf(m[r] - mn);
      float ls = 0.f;
      #pragma unroll
      for (int kb = 0; kb < 4; kb++) {
        float pv = __expf(acc_s[kb][r] - mn);
        p[kb][r] = pv;
        ls += pv;
      }
      ls += __shfl_xor(ls, 1);
      ls += __shfl_xor(ls, 2);
      ls += __shfl_xor(ls, 4);
      ls += __shfl_xor(ls, 8);
      l[r] = l[r] * corr[r] + ls;
      m[r] = mn;
    }
    // rescale O
    #pragma unroll
    for (int d = 0; d < 4; d++)
      #pragma unroll
      for (int r = 0; r < 4; r++) acc_o[d][r] *= corr[r];
    // write P to per-wave LDS (row=q_local, col=key)
    #pragma unroll
    for (int r = 0; r < 4; r++) {
      int row = kg * 4 + r;
      #pragma unroll
      for (int kb = 0; kb < 4; kb++)
        *(_Float16*)(PsB + row * 128 + SWZP(row, lr * 2 + kb * 32)) = (_Float16)p[kb][r];
    }
    __syncthreads();

    // PV: O[q][d] += P[q][key] * V[key][d]
    #pragma unroll
    for (int ks = 0; ks < 2; ks++) {
      f16x8 pA = *(const f16x8*)(PsB + lr * 128 + SWZP(lr, kg * 16 + ks * 64));
      #pragma unroll
      for (int dblk = 0; dblk < 4; dblk++) {
        f16x8 vB;
        #pragma unroll
        for (int j = 0; j < 8; j++) {
          int key = ks * 32 + kg * 8 + j;
          vB[j] = *(const _Float16*)(VsB + key * 128 + SWZB(key, dblk * 32 + lr * 2));
        }
        acc_o[dblk] = __builtin_amdgcn_mfma_f32_16x16x32_f16(pA, vB, acc_o[dblk], 0, 0, 0);
      }
    }
  }

  // epilogue: normalize, write f16 O in (b, t, h*64+d) layout
  #pragma unroll
  for (int r = 0; r < 4; r++) {
    float invl = 1.f / l[r];
    int q = q0 + wid * 16 + kg * 4 + r;
    _Float16* orow = O + ((size_t)b * NTOT + q) * CDIM + h * 64;
    #pragma unroll
    for (int dblk = 0; dblk < 4; dblk++)
      orow[dblk * 16 + lr] = (_Float16)(acc_o[dblk][r] * invl);
  }
}

// ---- second norm+modulate on x1 -> fp16 mlpin ----
__global__ __launch_bounds__(256) void k_rmsmod2(
    const float* __restrict__ x1,
    const float* __restrict__ adap, const float* __restrict__ adad,
    const float* __restrict__ g2p, const float* __restrict__ g2d,
    _Float16* __restrict__ mlpin) {
  int r = blockIdx.x;
  bool pix = r < 4096;
  int b = pix ? (r >> 10) : ((r - 4096) >> 8);
  const float* ada = pix ? adap : adad;
  const float* g   = pix ? g2p : g2d;
  const float* src = x1 + (size_t)r * CDIM;
  int tid = threadIdx.x;
  float vals[4];
  float ss = 0.f;
  #pragma unroll
  for (int i = 0; i < 4; i++) {
    float x = src[tid + i * 256];
    vals[i] = x;
    ss += x * x;
  }
  ss = blockReduceSum256(ss);
  float inv = 1.f / sqrtf(ss * (1.f / CDIM) + EPSF);
  _Float16* dst = mlpin + (size_t)r * CDIM;
  #pragma unroll
  for (int i = 0; i < 4; i++) {
    int cx = tid + i * 256;
    float sh = ada[b * N6C + 3 * CDIM + cx];
    float sl = ada[b * N6C + 4 * CDIM + cx];
    dst[cx] = (_Float16)(vals[i] * inv * g[cx] * (1.f + sl) + sh);
  }
}

// ---- swiglu gate ----
__global__ void k_swiglu(const _Float16* __restrict__ h12, _Float16* __restrict__ hg) {
  int r = blockIdx.x;
  const _Float16* h1 = h12 + (size_t)r * N12;
  const _Float16* h2 = h1 + HID;
  _Float16* o = hg + (size_t)r * HIDPAD;
  for (int j = threadIdx.x; j < HIDPAD; j += 256) {
    float v = 0.f;
    if (j < HID) {
      float a = (float)h1[j];
      v = (a / (1.f + expf(-a))) * (float)h2[j];
    }
    o[j] = (_Float16)v;
  }
}

extern "C" void kernel_launch(void* const* d_in, const int* in_sizes, int n_in,
                              void* d_out, int out_size, void* d_ws, size_t ws_size,
                              hipStream_t stream) {
  const float* x_pixel = (const float*)d_in[0];
  const float* x_dino  = (const float*)d_in[1];
  const float* c       = (const float*)d_in[2];
  const float* w_ada_p = (const float*)d_in[3];
  const float* b_ada_p = (const float*)d_in[4];
  const float* w_ada_d = (const float*)d_in[5];
  const float* b_ada_d = (const float*)d_in[6];
  const float* g_n1p   = (const float*)d_in[7];
  const float* g_n1d   = (const float*)d_in[8];
  const float* g_n2p   = (const float*)d_in[9];
  const float* g_n2d   = (const float*)d_in[10];
  const float* w_qkv   = (const float*)d_in[11];
  const float* b_qkv   = (const float*)d_in[12];
  const float* g_qn    = (const float*)d_in[13];
  const float* g_kn    = (const float*)d_in[14];
  const float* w_proj  = (const float*)d_in[15];
  const float* b_proj  = (const float*)d_in[16];
  const float* w12_p   = (const float*)d_in[17];
  const float* b12_p   = (const float*)d_in[18];
  const float* w3_p    = (const float*)d_in[19];
  const float* b3_p    = (const float*)d_in[20];
  const float* w12_d   = (const float*)d_in[21];
  const float* b12_d   = (const float*)d_in[22];
  const float* w3_d    = (const float*)d_in[23];
  const float* b3_d    = (const float*)d_in[24];
  const int*   blk     = (const int*)d_in[25];
  float* out = (float*)d_out;
  float* ws  = (float*)d_ws;

  float* sc     = ws + OFF_SC;
  float* ada_p  = ws + OFF_ADAP;
  float* ada_d  = ws + OFF_ADAD;
  float* rope   = ws + OFF_ROPE;
  _Float16* wtqkv  = (_Float16*)(ws + OFF_WTQKV);
  _Float16* wtproj = (_Float16*)(ws + OFF_WTPROJ);
  _Float16* wt12p  = (_Float16*)(ws + OFF_WT12P);
  _Float16* wt12d  = (_Float16*)(ws + OFF_WT12D);
  _Float16* wt3p   = (_Float16*)(ws + OFF_WT3P);
  _Float16* wt3d   = (_Float16*)(ws + OFF_WT3D);
  _Float16* actA   = (_Float16*)(ws + OFF_A);   // xc16 -> O16 -> mlpin16
  float*    qkv    = ws + OFF_B;                // fp32 [5120][3072]
  _Float16* h12f   = (_Float16*)(ws + OFF_B);   // later f16 [5120][5460]
  _Float16* Qh     = (_Float16*)(ws + OFF_C);              // f16 [64][1280][64]
  _Float16* Kh     = (_Float16*)(ws + OFF_C + 2621440);
  _Float16* Vh     = (_Float16*)(ws + OFF_C + 5242880);
  _Float16* hgate  = (_Float16*)(ws + OFF_C);   // later f16 [5120][2752]
  float*    x1     = ws + OFF_X1;

  hipLaunchKernelGGL(k_silu, dim3(16), dim3(256), 0, stream, c, sc, BATCH * CDIM);
  hipLaunchKernelGGL(k_ada, dim3(24, 2), dim3(256), 0, stream,
                     sc, w_ada_p, b_ada_p, w_ada_d, b_ada_d, ada_p, ada_d);
  hipLaunchKernelGGL(k_ropetab, dim3(NP), dim3(64), 0, stream, rope);
  hipLaunchKernelGGL(k_wtrans, dim3(3072 / 32, 1024 / 32), dim3(256), 0, stream,
                     w_qkv, wtqkv, 1024, 3072, 1024);
  hipLaunchKernelGGL(k_wtrans, dim3(1024 / 32, 1024 / 32), dim3(256), 0, stream,
                     w_proj, wtproj, 1024, 1024, 1024);
  hipLaunchKernelGGL(k_wtrans, dim3(N12PAD / 32, 1024 / 32), dim3(256), 0, stream,
                     w12_p, wt12p, 1024, N12, 1024);
  hipLaunchKernelGGL(k_wtrans, dim3(N12PAD / 32, 1024 / 32), dim3(256), 0, stream,
                     w12_d, wt12d, 1024, N12, 1024);
  hipLaunchKernelGGL(k_wtrans, dim3(1024 / 32, HIDPAD / 32), dim3(256), 0, stream,
                     w3_p, wt3p, HID, 1024, HIDPAD);
  hipLaunchKernelGGL(k_wtrans, dim3(1024 / 32, HIDPAD / 32), dim3(256), 0, stream,
                     w3_d, wt3d, HID, 1024, HIDPAD);

  hipLaunchKernelGGL(k_rmsmod1, dim3(BATCH * NTOT), dim3(256), 0, stream,
                     x_pixel, x_dino, ada_p, ada_d, g_n1p, g_n1d, actA);
  hipLaunchKernelGGL(k_hgemm<0>, dim3(3072 / 128, 5120 / 128), dim3(256), 0, stream,
                     actA, wtqkv, b_qkv, qkv, (_Float16*)nullptr,
                     nullptr, nullptr, nullptr, nullptr, 5120, 3072, 1024, 0);
  hipLaunchKernelGGL(k_qkvsplit, dim3(NTOT, BATCH), dim3(256), 0, stream,
                     qkv, g_qn, g_kn, rope, Qh, Kh, Vh);
  hipLaunchKernelGGL(k_attn, dim3(NTOT / 64, BATCH * NH), dim3(256), 0, stream,
                     Qh, Kh, Vh, blk, actA);   // actA now O16
  hipLaunchKernelGGL(k_hgemm<2>, dim3(1024 / 128, 5120 / 128), dim3(256), 0, stream,
                     actA, wtproj, b_proj, x1, (_Float16*)nullptr,
                     x_pixel, x_dino, ada_p, ada_d, 5120, 1024, 1024, 0);
  hipLaunchKernelGGL(k_rmsmod2, dim3(5120), dim3(256), 0, stream,
                     x1, ada_p, ada_d, g_n2p, g_n2d, actA);  // actA now mlpin16
  hipLaunchKernelGGL(k_hgemm<1>, dim3(N12PAD / 128, 4096 / 128), dim3(256), 0, stream,
                     actA, wt12p, b12_p, nullptr, h12f,
                     nullptr, nullptr, nullptr, nullptr, 4096, N12, 1024, 0);
  hipLaunchKernelGGL(k_hgemm<1>, dim3(N12PAD / 128, 1024 / 128), dim3(256), 0, stream,
                     actA + (size_t)4096 * CDIM, wt12d, b12_d, nullptr,
                     h12f + (size_t)4096 * N12,
                     nullptr, nullptr, nullptr, nullptr, 1024, N12, 1024, 0);
  hipLaunchKernelGGL(k_swiglu, dim3(5120), dim3(256), 0, stream, h12f, hgate);
  hipLaunchKernelGGL(k_hgemm<3>, dim3(1024 / 128, 4096 / 128), dim3(256), 0, stream,
                     hgate, wt3p, b3_p, out, (_Float16*)nullptr,
                     x1, nullptr, ada_p, nullptr, 4096, 1024, HIDPAD, 1024);
  hipLaunchKernelGGL(k_hgemm<3>, dim3(1024 / 128, 1024 / 128), dim3(256), 0, stream,
                     hgate + (size_t)4096 * HIDPAD, wt3d, b3_d, out + (size_t)4096 * CDIM,
                     (_Float16*)nullptr,
                     x1 + (size_t)4096 * CDIM, nullptr, ada_d, nullptr, 1024, 1024, HIDPAD, 256);
}